// Round 1
// baseline (8685.674 us; speedup 1.0000x reference)
//
#include <hip/hip_runtime.h>
#include <math.h>

#define HDIM 128

// ---------------- degree / norm ----------------
__global__ __launch_bounds__(256) void k_init_deg(float* deg, int n) {
    int i = blockIdx.x * 256 + threadIdx.x;
    if (i < n) deg[i] = 1.0f;   // self-loop contributes 1
}

__global__ __launch_bounds__(256) void k_accum_deg(const int* __restrict__ dst, float* deg, int E) {
    int e = blockIdx.x * 256 + threadIdx.x;
    if (e < E) unsafeAtomicAdd(&deg[dst[e]], 1.0f);
}

__global__ __launch_bounds__(256) void k_rsqrt(float* deg, int n) {
    int i = blockIdx.x * 256 + threadIdx.x;
    if (i < n) deg[i] = rsqrtf(deg[i]);   // deg >= 1 always
}

// ---------------- GEMM: C[M x 128] = (relu?)A[M x K] @ W[K x 128] + bias ----------------
// BM=64, BN=128, KB=32. 256 threads; per-thread 8 rows x 4 cols.
__global__ __launch_bounds__(256) void k_gemm(
    const float* __restrict__ A, const float* __restrict__ W,
    const float* __restrict__ bias, float* __restrict__ C,
    int M, int K, int relu_in)
{
    __shared__ float sA[32][68];    // [k][row], A transposed, pad 68 (16B-aligned stride)
    __shared__ float sW[32][132];   // [k][col]
    const int t  = threadIdx.x;
    const int tx = t & 31;          // col group: cols tx*4 .. +3
    const int ty = t >> 5;          // row group: rows ty*8 .. +7
    const int row0 = blockIdx.x * 64;

    float acc[8][4];
#pragma unroll
    for (int r = 0; r < 8; r++)
#pragma unroll
        for (int j = 0; j < 4; j++) acc[r][j] = 0.f;

    for (int k0 = 0; k0 < K; k0 += 32) {
        // stage A tile (64 rows x 32 k) transposed into LDS
#pragma unroll
        for (int i = 0; i < 2; i++) {
            int s = t + i * 256;          // 512 float4 slots
            int row = s >> 3, kq = s & 7;
            int grow = row0 + row;
            float4 v = make_float4(0.f, 0.f, 0.f, 0.f);
            if (grow < M) v = *(const float4*)(A + (size_t)grow * K + k0 + kq * 4);
            if (relu_in) {
                v.x = fmaxf(v.x, 0.f); v.y = fmaxf(v.y, 0.f);
                v.z = fmaxf(v.z, 0.f); v.w = fmaxf(v.w, 0.f);
            }
            sA[kq * 4 + 0][row] = v.x;
            sA[kq * 4 + 1][row] = v.y;
            sA[kq * 4 + 2][row] = v.z;
            sA[kq * 4 + 3][row] = v.w;
        }
        // stage W tile (32 k x 128 cols)
#pragma unroll
        for (int i = 0; i < 4; i++) {
            int s = t + i * 256;          // 1024 float4 slots
            int kk = s >> 5, cq = s & 31;
            float4 v = *(const float4*)(W + (size_t)(k0 + kk) * HDIM + cq * 4);
            *(float4*)&sW[kk][cq * 4] = v;
        }
        __syncthreads();
#pragma unroll
        for (int kk = 0; kk < 32; kk++) {
            float4 a0 = *(float4*)&sA[kk][ty * 8];
            float4 a1 = *(float4*)&sA[kk][ty * 8 + 4];
            float4 w  = *(float4*)&sW[kk][tx * 4];
            float av[8] = {a0.x, a0.y, a0.z, a0.w, a1.x, a1.y, a1.z, a1.w};
            float wv[4] = {w.x, w.y, w.z, w.w};
#pragma unroll
            for (int r = 0; r < 8; r++)
#pragma unroll
                for (int j = 0; j < 4; j++) acc[r][j] += av[r] * wv[j];
        }
        __syncthreads();
    }
    float4 b = make_float4(0.f, 0.f, 0.f, 0.f);
    if (bias) b = *(const float4*)(bias + tx * 4);
#pragma unroll
    for (int r = 0; r < 8; r++) {
        int grow = row0 + ty * 8 + r;
        if (grow < M) {
            float4 o = make_float4(acc[r][0] + b.x, acc[r][1] + b.y,
                                   acc[r][2] + b.z, acc[r][3] + b.w);
            *(float4*)(C + (size_t)grow * HDIM + tx * 4) = o;
        }
    }
}

// ---------------- conv init: out = dis[i]^2 * xw[i] + bias (self-loop term + bias) ----------------
__global__ __launch_bounds__(256) void k_conv_init(
    float* __restrict__ out, const float* __restrict__ xw,
    const float* __restrict__ dis, const float* __restrict__ bias, int n)
{
    int idx = blockIdx.x * 256 + threadIdx.x;   // n*32 total
    if (idx >= n * 32) return;
    int i = idx >> 5, fq = idx & 31;
    float d = dis[i];
    float d2 = d * d;
    float4 v = *(const float4*)(xw + (size_t)i * HDIM + fq * 4);
    float4 b = *(const float4*)(bias + fq * 4);
    float4 o = make_float4(d2 * v.x + b.x, d2 * v.y + b.y, d2 * v.z + b.z, d2 * v.w + b.w);
    *(float4*)(out + (size_t)i * HDIM + fq * 4) = o;
}

// ---------------- scatter: out[dst] += dis[s]*dis[d] * xw[src]  (32 lanes/edge, float4) ----------------
__global__ __launch_bounds__(256) void k_scatter(
    const int* __restrict__ ei, const float* __restrict__ dis,
    const float* __restrict__ xw, float* __restrict__ out, int E)
{
    int gid = blockIdx.x * 256 + threadIdx.x;
    int e = gid >> 5;
    if (e >= E) return;
    int sub = gid & 31;
    int s = ei[e], d = ei[E + e];
    float nrm = dis[s] * dis[d];
    float4 v = *(const float4*)(xw + (size_t)s * HDIM + sub * 4);
    float* o = out + (size_t)d * HDIM + sub * 4;
    unsafeAtomicAdd(o + 0, nrm * v.x);
    unsafeAtomicAdd(o + 1, nrm * v.y);
    unsafeAtomicAdd(o + 2, nrm * v.z);
    unsafeAtomicAdd(o + 3, nrm * v.w);
}

// ---------------- edge scorer: sigmoid(relu(P[s]+Q[d]) . w2 + b2) ----------------
__global__ __launch_bounds__(256) void k_edge_score(
    const int* __restrict__ ei, const float* __restrict__ P, const float* __restrict__ Q,
    const float* __restrict__ w2, const float* __restrict__ b2,
    float* __restrict__ out, int E)
{
    int gid = blockIdx.x * 256 + threadIdx.x;
    int e = gid >> 5;
    if (e >= E) return;
    int sub = gid & 31;
    int s = ei[e], d = ei[E + e];
    float4 p = *(const float4*)(P + (size_t)s * HDIM + sub * 4);
    float4 q = *(const float4*)(Q + (size_t)d * HDIM + sub * 4);
    float4 w = *(const float4*)(w2 + sub * 4);
    float h0 = fmaxf(p.x + q.x, 0.f);
    float h1 = fmaxf(p.y + q.y, 0.f);
    float h2 = fmaxf(p.z + q.z, 0.f);
    float h3 = fmaxf(p.w + q.w, 0.f);
    float part = h0 * w.x + h1 * w.y + h2 * w.z + h3 * w.w;
#pragma unroll
    for (int off = 16; off; off >>= 1) part += __shfl_xor(part, off, 64);
    if (sub == 0) out[e] = 1.f / (1.f + expf(-(part + b2[0])));
}

extern "C" void kernel_launch(void* const* d_in, const int* in_sizes, int n_in,
                              void* d_out, int out_size, void* d_ws, size_t ws_size,
                              hipStream_t stream) {
    const float* nf   = (const float*)d_in[0];
    const int*   ei   = (const int*)d_in[1];
    const float* ew1  = (const float*)d_in[2];
    const float* eb1  = (const float*)d_in[3];
    const float* ew2  = (const float*)d_in[4];
    const float* eb2  = (const float*)d_in[5];
    const float* cw1  = (const float*)d_in[6];
    const float* cb1  = (const float*)d_in[7];
    const float* cw2  = (const float*)d_in[8];
    const float* cb2  = (const float*)d_in[9];
    const float* cw3  = (const float*)d_in[10];
    const float* cb3  = (const float*)d_in[11];
    const float* clw1 = (const float*)d_in[12];
    const float* clb1 = (const float*)d_in[13];
    const float* clw2 = (const float*)d_in[14];
    const float* clb2 = (const float*)d_in[15];
    float* out = (float*)d_out;

    const int FD = 256;
    const int N = in_sizes[0] / FD;
    const int E = in_sizes[1] / 2;

    float* ws = (float*)d_ws;
    float* deg = ws;                                  // N floats -> becomes dis after rsqrt
    size_t degpad = ((size_t)N + 255) & ~(size_t)255;
    float* bufA = ws + degpad;                        // N*H each
    float* bufB = bufA + (size_t)N * HDIM;
    float* bufC = bufB + (size_t)N * HDIM;

    int ng = (N + 255) / 256;
    int eg = (E + 255) / 256;
    int gemm_grid = (N + 63) / 64;
    int ig = (N * 32 + 255) / 256;
    long long ethreads = (long long)E * 32;
    int sg = (int)((ethreads + 255) / 256);

    // degrees -> dis
    k_init_deg<<<ng, 256, 0, stream>>>(deg, N);
    k_accum_deg<<<eg, 256, 0, stream>>>(ei + E, deg, E);
    k_rsqrt<<<ng, 256, 0, stream>>>(deg, N);

    // encoder: bufA = nf@ew1+eb1 (pre-relu), bufB = relu(bufA)@ew2+eb2 = x0
    k_gemm<<<gemm_grid, 256, 0, stream>>>(nf, ew1, eb1, bufA, N, 256, 0);
    k_gemm<<<gemm_grid, 256, 0, stream>>>(bufA, ew2, eb2, bufB, N, 128, 1);

    // conv1: xw=bufA = bufB@cw1 ; out=bufC
    k_gemm<<<gemm_grid, 256, 0, stream>>>(bufB, cw1, nullptr, bufA, N, 128, 0);
    k_conv_init<<<ig, 256, 0, stream>>>(bufC, bufA, deg, cb1, N);
    k_scatter<<<sg, 256, 0, stream>>>(ei, deg, bufA, bufC, E);
    // conv2: xw=bufB = relu(bufC)@cw2 ; out=bufA
    k_gemm<<<gemm_grid, 256, 0, stream>>>(bufC, cw2, nullptr, bufB, N, 128, 1);
    k_conv_init<<<ig, 256, 0, stream>>>(bufA, bufB, deg, cb2, N);
    k_scatter<<<sg, 256, 0, stream>>>(ei, deg, bufB, bufA, E);
    // conv3: xw=bufC = relu(bufA)@cw3 ; out=bufB = x3 (no relu)
    k_gemm<<<gemm_grid, 256, 0, stream>>>(bufA, cw3, nullptr, bufC, N, 128, 1);
    k_conv_init<<<ig, 256, 0, stream>>>(bufB, bufC, deg, cb3, N);
    k_scatter<<<sg, 256, 0, stream>>>(ei, deg, bufC, bufB, E);

    // edge classifier split: P = x3@W1_top + b1 (bufA), Q = x3@W1_bot (bufC)
    k_gemm<<<gemm_grid, 256, 0, stream>>>(bufB, clw1, clb1, bufA, N, 128, 0);
    k_gemm<<<gemm_grid, 256, 0, stream>>>(bufB, clw1 + 128 * HDIM, nullptr, bufC, N, 128, 0);

    k_edge_score<<<sg, 256, 0, stream>>>(ei, bufA, bufC, clw2, clb2, out, E);
}

// Round 2
// 1140.822 us; speedup vs baseline: 7.6135x; 7.6135x over previous
//
#include <hip/hip_runtime.h>
#include <math.h>

#define HDIM 128

// ---------------- CSR build ----------------
__global__ __launch_bounds__(256) void k_count(const int* __restrict__ dst, int* __restrict__ cnt, int E) {
    int e = blockIdx.x * 256 + threadIdx.x;
    if (e < E) atomicAdd(&cnt[dst[e]], 1);
}

// block-local exclusive scan; partial[b] = block total
__global__ __launch_bounds__(256) void k_scan1(const int* __restrict__ cnt, int* __restrict__ row_ptr,
                                               int* __restrict__ partial, int n) {
    __shared__ int sm[256];
    int tid = threadIdx.x;
    int i = blockIdx.x * 256 + tid;
    int v = (i < n) ? cnt[i] : 0;
    sm[tid] = v;
    __syncthreads();
    int acc = v;
    for (int off = 1; off < 256; off <<= 1) {
        int t = (tid >= off) ? sm[tid - off] : 0;
        __syncthreads();
        acc += t;
        sm[tid] = acc;
        __syncthreads();
    }
    if (i < n) row_ptr[i] = acc - v;          // exclusive, block-local
    if (tid == 255) partial[blockIdx.x] = acc; // block total
}

// single-block scan of block totals -> exclusive offsets (nb <= 256)
__global__ __launch_bounds__(256) void k_scan2(int* __restrict__ partial, int nb) {
    __shared__ int sm[256];
    int tid = threadIdx.x;
    int v = (tid < nb) ? partial[tid] : 0;
    sm[tid] = v;
    __syncthreads();
    int acc = v;
    for (int off = 1; off < 256; off <<= 1) {
        int t = (tid >= off) ? sm[tid - off] : 0;
        __syncthreads();
        acc += t;
        sm[tid] = acc;
        __syncthreads();
    }
    partial[tid] = acc - v;                   // exclusive
}

// finalize row_ptr, init cursor, compute dis = rsqrt(1+deg)
__global__ __launch_bounds__(256) void k_scan3(const int* __restrict__ cnt, int* __restrict__ row_ptr,
                                               const int* __restrict__ partial, int* __restrict__ cursor,
                                               float* __restrict__ dis, int n, int E) {
    int i = blockIdx.x * 256 + threadIdx.x;
    if (i == 0) row_ptr[n] = E;
    if (i >= n) return;
    int rp = row_ptr[i] + partial[blockIdx.x];
    row_ptr[i] = rp;
    cursor[i] = rp;
    dis[i] = rsqrtf(1.0f + (float)cnt[i]);
}

__global__ __launch_bounds__(256) void k_fill(const int* __restrict__ src, const int* __restrict__ dst,
                                              int* __restrict__ cursor, int* __restrict__ col, int E) {
    int e = blockIdx.x * 256 + threadIdx.x;
    if (e >= E) return;
    int pos = atomicAdd(&cursor[dst[e]], 1);
    col[pos] = src[e];
}

// ---------------- GEMM: C[M x 128] = (relu?)A[M x K] @ W[K x 128] + bias ----------------
__global__ __launch_bounds__(256) void k_gemm(
    const float* __restrict__ A, const float* __restrict__ W,
    const float* __restrict__ bias, float* __restrict__ C,
    int M, int K, int relu_in)
{
    __shared__ float sA[32][68];
    __shared__ float sW[32][132];
    const int t  = threadIdx.x;
    const int tx = t & 31;
    const int ty = t >> 5;
    const int row0 = blockIdx.x * 64;

    float acc[8][4];
#pragma unroll
    for (int r = 0; r < 8; r++)
#pragma unroll
        for (int j = 0; j < 4; j++) acc[r][j] = 0.f;

    for (int k0 = 0; k0 < K; k0 += 32) {
#pragma unroll
        for (int i = 0; i < 2; i++) {
            int s = t + i * 256;
            int row = s >> 3, kq = s & 7;
            int grow = row0 + row;
            float4 v = make_float4(0.f, 0.f, 0.f, 0.f);
            if (grow < M) v = *(const float4*)(A + (size_t)grow * K + k0 + kq * 4);
            if (relu_in) {
                v.x = fmaxf(v.x, 0.f); v.y = fmaxf(v.y, 0.f);
                v.z = fmaxf(v.z, 0.f); v.w = fmaxf(v.w, 0.f);
            }
            sA[kq * 4 + 0][row] = v.x;
            sA[kq * 4 + 1][row] = v.y;
            sA[kq * 4 + 2][row] = v.z;
            sA[kq * 4 + 3][row] = v.w;
        }
#pragma unroll
        for (int i = 0; i < 4; i++) {
            int s = t + i * 256;
            int kk = s >> 5, cq = s & 31;
            float4 v = *(const float4*)(W + (size_t)(k0 + kk) * HDIM + cq * 4);
            *(float4*)&sW[kk][cq * 4] = v;
        }
        __syncthreads();
#pragma unroll
        for (int kk = 0; kk < 32; kk++) {
            float4 a0 = *(float4*)&sA[kk][ty * 8];
            float4 a1 = *(float4*)&sA[kk][ty * 8 + 4];
            float4 w  = *(float4*)&sW[kk][tx * 4];
            float av[8] = {a0.x, a0.y, a0.z, a0.w, a1.x, a1.y, a1.z, a1.w};
            float wv[4] = {w.x, w.y, w.z, w.w};
#pragma unroll
            for (int r = 0; r < 8; r++)
#pragma unroll
                for (int j = 0; j < 4; j++) acc[r][j] += av[r] * wv[j];
        }
        __syncthreads();
    }
    float4 b = make_float4(0.f, 0.f, 0.f, 0.f);
    if (bias) b = *(const float4*)(bias + tx * 4);
#pragma unroll
    for (int r = 0; r < 8; r++) {
        int grow = row0 + ty * 8 + r;
        if (grow < M) {
            float4 o = make_float4(acc[r][0] + b.x, acc[r][1] + b.y,
                                   acc[r][2] + b.z, acc[r][3] + b.w);
            *(float4*)(C + (size_t)grow * HDIM + tx * 4) = o;
        }
    }
}

// ---------------- aggregate: out[i] = dis[i]*(dis[i]*xw[i] + sum_nbr dis[s]*xw[s]) + b ----------------
// one wave (64 lanes) per node; float2 per lane covers H=128
__global__ __launch_bounds__(256) void k_aggregate(
    const int* __restrict__ row_ptr, const int* __restrict__ col,
    const float* __restrict__ dis, const float* __restrict__ xw,
    const float* __restrict__ bias, float* __restrict__ out, int n)
{
    int wid = (blockIdx.x * 256 + threadIdx.x) >> 6;
    if (wid >= n) return;
    int lane = threadIdx.x & 63;
    float di = dis[wid];
    float2 acc = *(const float2*)(xw + (size_t)wid * HDIM + lane * 2);
    acc.x *= di; acc.y *= di;   // self-loop: dis[i]*xw[i]
    int beg = row_ptr[wid], end = row_ptr[wid + 1];
    int j = beg;
    for (; j + 1 < end; j += 2) {
        int s0 = col[j], s1 = col[j + 1];
        float d0 = dis[s0], d1 = dis[s1];
        float2 v0 = *(const float2*)(xw + (size_t)s0 * HDIM + lane * 2);
        float2 v1 = *(const float2*)(xw + (size_t)s1 * HDIM + lane * 2);
        acc.x += d0 * v0.x + d1 * v1.x;
        acc.y += d0 * v0.y + d1 * v1.y;
    }
    if (j < end) {
        int s = col[j];
        float ds = dis[s];
        float2 v = *(const float2*)(xw + (size_t)s * HDIM + lane * 2);
        acc.x += ds * v.x; acc.y += ds * v.y;
    }
    float2 b = *(const float2*)(bias + lane * 2);
    float2 o = make_float2(di * acc.x + b.x, di * acc.y + b.y);
    *(float2*)(out + (size_t)wid * HDIM + lane * 2) = o;
}

// ---------------- edge scorer: sigmoid(relu(P[s]+Q[d]) . w2 + b2) ----------------
__global__ __launch_bounds__(256) void k_edge_score(
    const int* __restrict__ ei, const float* __restrict__ P, const float* __restrict__ Q,
    const float* __restrict__ w2, const float* __restrict__ b2,
    float* __restrict__ out, int E)
{
    int gid = blockIdx.x * 256 + threadIdx.x;
    int e = gid >> 5;
    if (e >= E) return;
    int sub = gid & 31;
    int s = ei[e], d = ei[E + e];
    float4 p = *(const float4*)(P + (size_t)s * HDIM + sub * 4);
    float4 q = *(const float4*)(Q + (size_t)d * HDIM + sub * 4);
    float4 w = *(const float4*)(w2 + sub * 4);
    float h0 = fmaxf(p.x + q.x, 0.f);
    float h1 = fmaxf(p.y + q.y, 0.f);
    float h2 = fmaxf(p.z + q.z, 0.f);
    float h3 = fmaxf(p.w + q.w, 0.f);
    float part = h0 * w.x + h1 * w.y + h2 * w.z + h3 * w.w;
#pragma unroll
    for (int off = 16; off; off >>= 1) part += __shfl_xor(part, off, 64);
    if (sub == 0) out[e] = 1.f / (1.f + expf(-(part + b2[0])));
}

extern "C" void kernel_launch(void* const* d_in, const int* in_sizes, int n_in,
                              void* d_out, int out_size, void* d_ws, size_t ws_size,
                              hipStream_t stream) {
    const float* nf   = (const float*)d_in[0];
    const int*   ei   = (const int*)d_in[1];
    const float* ew1  = (const float*)d_in[2];
    const float* eb1  = (const float*)d_in[3];
    const float* ew2  = (const float*)d_in[4];
    const float* eb2  = (const float*)d_in[5];
    const float* cw1  = (const float*)d_in[6];
    const float* cb1  = (const float*)d_in[7];
    const float* cw2  = (const float*)d_in[8];
    const float* cb2  = (const float*)d_in[9];
    const float* cw3  = (const float*)d_in[10];
    const float* cb3  = (const float*)d_in[11];
    const float* clw1 = (const float*)d_in[12];
    const float* clb1 = (const float*)d_in[13];
    const float* clw2 = (const float*)d_in[14];
    const float* clb2 = (const float*)d_in[15];
    float* out = (float*)d_out;

    const int FD = 256;
    const int N = in_sizes[0] / FD;
    const int E = in_sizes[1] / 2;

    size_t Np = ((size_t)N + 256) & ~(size_t)255;   // >= N+1, 256-aligned
    float* ws = (float*)d_ws;
    float* dis     = ws;
    int*   cnt     = (int*)(ws + Np);
    int*   row_ptr = cnt + Np;
    int*   cursor  = row_ptr + Np;
    int*   partial = cursor + Np;
    int*   col     = partial + 256;
    size_t colend  = 4 * Np + 256 + (size_t)E;
    colend = (colend + 255) & ~(size_t)255;
    float* bufA = ws + colend;
    float* bufB = bufA + (size_t)N * HDIM;
    float* bufC = bufB + (size_t)N * HDIM;

    int eg = (E + 255) / 256;
    int nb1 = (N + 255) / 256;               // 196 <= 256
    int gemm_grid = (N + 63) / 64;
    int ag = (N + 3) / 4;                    // 4 waves (nodes) per block
    long long ethreads = (long long)E * 32;
    int sg = (int)((ethreads + 255) / 256);

    // ---- CSR build ----
    hipMemsetAsync(cnt, 0, (Np) * sizeof(int), stream);
    k_count<<<eg, 256, 0, stream>>>(ei + E, cnt, E);
    k_scan1<<<nb1, 256, 0, stream>>>(cnt, row_ptr, partial, N);
    k_scan2<<<1, 256, 0, stream>>>(partial, nb1);
    k_scan3<<<nb1, 256, 0, stream>>>(cnt, row_ptr, partial, cursor, dis, N, E);
    k_fill<<<eg, 256, 0, stream>>>(ei, ei + E, cursor, col, E);

    // ---- encoder ----
    k_gemm<<<gemm_grid, 256, 0, stream>>>(nf, ew1, eb1, bufA, N, 256, 0);
    k_gemm<<<gemm_grid, 256, 0, stream>>>(bufA, ew2, eb2, bufB, N, 128, 1);

    // ---- conv1: xw in bufA, out bufC ----
    k_gemm<<<gemm_grid, 256, 0, stream>>>(bufB, cw1, nullptr, bufA, N, 128, 0);
    k_aggregate<<<ag, 256, 0, stream>>>(row_ptr, col, dis, bufA, cb1, bufC, N);
    // ---- conv2: xw in bufB, out bufA ----
    k_gemm<<<gemm_grid, 256, 0, stream>>>(bufC, cw2, nullptr, bufB, N, 128, 1);
    k_aggregate<<<ag, 256, 0, stream>>>(row_ptr, col, dis, bufB, cb2, bufA, N);
    // ---- conv3: xw in bufC, out bufB = x3 ----
    k_gemm<<<gemm_grid, 256, 0, stream>>>(bufA, cw3, nullptr, bufC, N, 128, 1);
    k_aggregate<<<ag, 256, 0, stream>>>(row_ptr, col, dis, bufC, cb3, bufB, N);

    // ---- edge classifier: P = x3@W1_top + b1 (bufA), Q = x3@W1_bot (bufC) ----
    k_gemm<<<gemm_grid, 256, 0, stream>>>(bufB, clw1, clb1, bufA, N, 128, 0);
    k_gemm<<<gemm_grid, 256, 0, stream>>>(bufB, clw1 + 128 * HDIM, nullptr, bufC, N, 128, 0);

    k_edge_score<<<sg, 256, 0, stream>>>(ei, bufA, bufC, clw2, clb2, out, E);
}

// Round 3
// 784.495 us; speedup vs baseline: 11.0717x; 1.4542x over previous
//
#include <hip/hip_runtime.h>
#include <math.h>

#define HDIM 128

typedef __attribute__((ext_vector_type(8))) short    bf16x8;
typedef __attribute__((ext_vector_type(4))) float    f32x4;
typedef __attribute__((ext_vector_type(8))) unsigned short u16x8;
typedef __attribute__((ext_vector_type(4))) unsigned short u16x4;

__device__ __forceinline__ float bf2f(unsigned short u) {
    union { unsigned int i; float f; } c; c.i = ((unsigned int)u) << 16; return c.f;
}
__device__ __forceinline__ float bf2f_lo(unsigned int u) {
    union { unsigned int i; float f; } c; c.i = u << 16; return c.f;
}
__device__ __forceinline__ float bf2f_hi(unsigned int u) {
    union { unsigned int i; float f; } c; c.i = u & 0xffff0000u; return c.f;
}
__device__ __forceinline__ unsigned short f2bf(float f) {
    union { float f; unsigned int i; } c; c.f = f;
    unsigned int r = (c.i + 0x7fffu + ((c.i >> 16) & 1u)) >> 16;
    return (unsigned short)r;
}

// ---------------- CSR build ----------------
__global__ __launch_bounds__(256) void k_count(const int* __restrict__ dst, int* __restrict__ cnt, int E) {
    int e = blockIdx.x * 256 + threadIdx.x;
    if (e < E) atomicAdd(&cnt[dst[e]], 1);
}

__global__ __launch_bounds__(256) void k_scan1(const int* __restrict__ cnt, int* __restrict__ row_ptr,
                                               int* __restrict__ partial, int n) {
    __shared__ int sm[256];
    int tid = threadIdx.x;
    int i = blockIdx.x * 256 + tid;
    int v = (i < n) ? cnt[i] : 0;
    sm[tid] = v;
    __syncthreads();
    int acc = v;
    for (int off = 1; off < 256; off <<= 1) {
        int t = (tid >= off) ? sm[tid - off] : 0;
        __syncthreads();
        acc += t;
        sm[tid] = acc;
        __syncthreads();
    }
    if (i < n) row_ptr[i] = acc - v;
    if (tid == 255) partial[blockIdx.x] = acc;
}

__global__ __launch_bounds__(256) void k_scan2(int* __restrict__ partial, int nb) {
    __shared__ int sm[256];
    int tid = threadIdx.x;
    int v = (tid < nb) ? partial[tid] : 0;
    sm[tid] = v;
    __syncthreads();
    int acc = v;
    for (int off = 1; off < 256; off <<= 1) {
        int t = (tid >= off) ? sm[tid - off] : 0;
        __syncthreads();
        acc += t;
        sm[tid] = acc;
        __syncthreads();
    }
    partial[tid] = acc - v;
}

__global__ __launch_bounds__(256) void k_scan3(const int* __restrict__ cnt, int* __restrict__ row_ptr,
                                               const int* __restrict__ partial, int* __restrict__ cursor,
                                               float* __restrict__ dis, int n, int E) {
    int i = blockIdx.x * 256 + threadIdx.x;
    if (i == 0) row_ptr[n] = E;
    if (i >= n) return;
    int rp = row_ptr[i] + partial[blockIdx.x];
    row_ptr[i] = rp;
    cursor[i] = rp;
    dis[i] = rsqrtf(1.0f + (float)cnt[i]);
}

__global__ __launch_bounds__(256) void k_fill(const int* __restrict__ src, const int* __restrict__ dst,
                                              int* __restrict__ cursor, int* __restrict__ col, int E) {
    int e = blockIdx.x * 256 + threadIdx.x;
    if (e >= E) return;
    int pos = atomicAdd(&cursor[dst[e]], 1);
    col[pos] = src[e];
}

// ---------------- weight prep: fp32 W[KxH] -> bf16 W^T[HxK] ----------------
struct WEnt { const float* src; unsigned short* dst; int K; };
struct WAll { WEnt w[7]; };

__global__ __launch_bounds__(256) void k_prep_w(WAll all) {
    WEnt e = all.w[blockIdx.y];
    int i = blockIdx.x * 256 + threadIdx.x;
    if (i >= e.K * HDIM) return;
    int k = i >> 7, c = i & 127;
    e.dst[(size_t)c * e.K + k] = f2bf(e.src[i]);
}

// ---------------- MFMA GEMM (bf16 A), K=128: C[Mx128] = X @ Wt^T + bias ----------------
// wave = 16 rows x 128 cols; operand-swap: a=W-frag, b=X-frag -> lane stores 4 contiguous cols.
__global__ __launch_bounds__(256) void k_gemm_b(
    const unsigned short* __restrict__ X, const unsigned short* __restrict__ Wt,
    const float* __restrict__ bias, unsigned short* __restrict__ C,
    int M, int relu_out)
{
    const int K = 128;
    int wave = threadIdx.x >> 6, lane = threadIdx.x & 63;
    int quad = lane >> 4, r = lane & 15;
    int row0 = blockIdx.x * 64 + wave * 16;
    if (row0 >= M) return;                       // M % 16 == 0
    const unsigned short* xp = X + (size_t)(row0 + r) * K + quad * 8;
    const unsigned short* wp = Wt + (size_t)r * K + quad * 8;
    f32x4 acc[8];
#pragma unroll
    for (int mt = 0; mt < 8; mt++) acc[mt] = (f32x4){0.f, 0.f, 0.f, 0.f};
#pragma unroll 2
    for (int k0 = 0; k0 < K; k0 += 32) {
        bf16x8 xf = *(const bf16x8*)(xp + k0);
#pragma unroll
        for (int mt = 0; mt < 8; mt++) {
            bf16x8 wf = *(const bf16x8*)(wp + (size_t)mt * 16 * K + k0);
            acc[mt] = __builtin_amdgcn_mfma_f32_16x16x32_bf16(wf, xf, acc[mt], 0, 0, 0);
        }
    }
    unsigned short* cp = C + (size_t)(row0 + r) * HDIM + quad * 4;
#pragma unroll
    for (int mt = 0; mt < 8; mt++) {
        u16x4 o;
#pragma unroll
        for (int j = 0; j < 4; j++) {
            float v = acc[mt][j];
            if (bias) v += bias[mt * 16 + quad * 4 + j];
            if (relu_out) v = fmaxf(v, 0.f);
            o[j] = f2bf(v);
        }
        *(u16x4*)(cp + mt * 16) = o;
    }
}

// ---------------- MFMA GEMM (fp32 A = node_features), K=256 ----------------
__global__ __launch_bounds__(256) void k_gemm_nf(
    const float* __restrict__ X, const unsigned short* __restrict__ Wt,
    const float* __restrict__ bias, unsigned short* __restrict__ C,
    int M, int relu_out)
{
    const int K = 256;
    int wave = threadIdx.x >> 6, lane = threadIdx.x & 63;
    int quad = lane >> 4, r = lane & 15;
    int row0 = blockIdx.x * 64 + wave * 16;
    if (row0 >= M) return;
    const float* xp = X + (size_t)(row0 + r) * K + quad * 8;
    const unsigned short* wp = Wt + (size_t)r * K + quad * 8;
    f32x4 acc[8];
#pragma unroll
    for (int mt = 0; mt < 8; mt++) acc[mt] = (f32x4){0.f, 0.f, 0.f, 0.f};
#pragma unroll 2
    for (int k0 = 0; k0 < K; k0 += 32) {
        float4 xa = *(const float4*)(xp + k0);
        float4 xb = *(const float4*)(xp + k0 + 4);
        bf16x8 xf;
        xf[0] = (short)f2bf(xa.x); xf[1] = (short)f2bf(xa.y);
        xf[2] = (short)f2bf(xa.z); xf[3] = (short)f2bf(xa.w);
        xf[4] = (short)f2bf(xb.x); xf[5] = (short)f2bf(xb.y);
        xf[6] = (short)f2bf(xb.z); xf[7] = (short)f2bf(xb.w);
#pragma unroll
        for (int mt = 0; mt < 8; mt++) {
            bf16x8 wf = *(const bf16x8*)(wp + (size_t)mt * 16 * K + k0);
            acc[mt] = __builtin_amdgcn_mfma_f32_16x16x32_bf16(wf, xf, acc[mt], 0, 0, 0);
        }
    }
    unsigned short* cp = C + (size_t)(row0 + r) * HDIM + quad * 4;
#pragma unroll
    for (int mt = 0; mt < 8; mt++) {
        u16x4 o;
#pragma unroll
        for (int j = 0; j < 4; j++) {
            float v = acc[mt][j];
            if (bias) v += bias[mt * 16 + quad * 4 + j];
            if (relu_out) v = fmaxf(v, 0.f);
            o[j] = f2bf(v);
        }
        *(u16x4*)(cp + mt * 16) = o;
    }
}

// ---------------- aggregate (bf16): out[i] = dis_i*(dis_i*xw[i] + sum dis_s*xw[s]) + b ----------------
// one wave per node; lane covers 2 features packed in one uint.
__global__ __launch_bounds__(256) void k_aggregate(
    const int* __restrict__ row_ptr, const int* __restrict__ col,
    const float* __restrict__ dis, const unsigned int* __restrict__ xw,
    const float* __restrict__ bias, unsigned int* __restrict__ out, int n, int relu_out)
{
    int wid = (blockIdx.x * 256 + threadIdx.x) >> 6;
    if (wid >= n) return;
    int lane = threadIdx.x & 63;
    float di = dis[wid];
    unsigned int sv = xw[(size_t)wid * 64 + lane];
    float ax = di * bf2f_lo(sv);
    float ay = di * bf2f_hi(sv);
    int beg = row_ptr[wid], end = row_ptr[wid + 1];
    int j = beg;
    for (; j + 3 < end; j += 4) {
        int s0 = col[j], s1 = col[j + 1], s2 = col[j + 2], s3 = col[j + 3];
        float d0 = dis[s0], d1 = dis[s1], d2 = dis[s2], d3 = dis[s3];
        unsigned int v0 = xw[(size_t)s0 * 64 + lane];
        unsigned int v1 = xw[(size_t)s1 * 64 + lane];
        unsigned int v2 = xw[(size_t)s2 * 64 + lane];
        unsigned int v3 = xw[(size_t)s3 * 64 + lane];
        ax += d0 * bf2f_lo(v0) + d1 * bf2f_lo(v1) + d2 * bf2f_lo(v2) + d3 * bf2f_lo(v3);
        ay += d0 * bf2f_hi(v0) + d1 * bf2f_hi(v1) + d2 * bf2f_hi(v2) + d3 * bf2f_hi(v3);
    }
    for (; j < end; j++) {
        int s = col[j];
        float ds = dis[s];
        unsigned int v = xw[(size_t)s * 64 + lane];
        ax += ds * bf2f_lo(v);
        ay += ds * bf2f_hi(v);
    }
    float ox = di * ax + bias[lane * 2];
    float oy = di * ay + bias[lane * 2 + 1];
    if (relu_out) { ox = fmaxf(ox, 0.f); oy = fmaxf(oy, 0.f); }
    out[(size_t)wid * 64 + lane] = (unsigned int)f2bf(ox) | ((unsigned int)f2bf(oy) << 16);
}

// ---------------- edge scorer (bf16 P/Q): sigmoid(relu(P[s]+Q[d]) . w2 + b2) ----------------
__global__ __launch_bounds__(256) void k_edge_score(
    const int* __restrict__ ei, const unsigned short* __restrict__ P,
    const unsigned short* __restrict__ Q,
    const float* __restrict__ w2, const float* __restrict__ b2,
    float* __restrict__ out, int E)
{
    int gid = blockIdx.x * 256 + threadIdx.x;
    int e = gid >> 4;
    if (e >= E) return;
    int sub = gid & 15;
    int s = ei[e], d = ei[E + e];
    u16x8 pv = *(const u16x8*)(P + (size_t)s * HDIM + sub * 8);
    u16x8 qv = *(const u16x8*)(Q + (size_t)d * HDIM + sub * 8);
    float part = 0.f;
#pragma unroll
    for (int j = 0; j < 8; j++) {
        float h = bf2f(pv[j]) + bf2f(qv[j]);
        h = fmaxf(h, 0.f);
        part += h * w2[sub * 8 + j];
    }
#pragma unroll
    for (int off = 8; off; off >>= 1) part += __shfl_xor(part, off, 16);
    if (sub == 0) out[e] = 1.f / (1.f + expf(-(part + b2[0])));
}

extern "C" void kernel_launch(void* const* d_in, const int* in_sizes, int n_in,
                              void* d_out, int out_size, void* d_ws, size_t ws_size,
                              hipStream_t stream) {
    const float* nf   = (const float*)d_in[0];
    const int*   ei   = (const int*)d_in[1];
    const float* ew1  = (const float*)d_in[2];
    const float* eb1  = (const float*)d_in[3];
    const float* ew2  = (const float*)d_in[4];
    const float* eb2  = (const float*)d_in[5];
    const float* cw1  = (const float*)d_in[6];
    const float* cb1  = (const float*)d_in[7];
    const float* cw2  = (const float*)d_in[8];
    const float* cb2  = (const float*)d_in[9];
    const float* cw3  = (const float*)d_in[10];
    const float* cb3  = (const float*)d_in[11];
    const float* clw1 = (const float*)d_in[12];
    const float* clb1 = (const float*)d_in[13];
    const float* clw2 = (const float*)d_in[14];
    const float* clb2 = (const float*)d_in[15];
    float* out = (float*)d_out;

    const int FD = 256;
    const int N = in_sizes[0] / FD;
    const int E = in_sizes[1] / 2;

    size_t Np = ((size_t)N + 256) & ~(size_t)255;
    char* w = (char*)d_ws;
    float* dis     = (float*)w;            w += Np * 4;
    int*   cnt     = (int*)w;              w += Np * 4;
    int*   row_ptr = (int*)w;              w += Np * 4;
    int*   cursor  = (int*)w;              w += Np * 4;
    int*   partial = (int*)w;              w += 1024;
    int*   col     = (int*)w;              w += (((size_t)E * 4) + 255) & ~(size_t)255;
    unsigned short* bufA = (unsigned short*)w;  w += (size_t)N * HDIM * 2;
    unsigned short* bufB = (unsigned short*)w;  w += (size_t)N * HDIM * 2;
    unsigned short* bufC = (unsigned short*)w;  w += (size_t)N * HDIM * 2;
    unsigned short* wtE1 = (unsigned short*)w;  w += 256 * HDIM * 2;
    unsigned short* wtE2 = (unsigned short*)w;  w += 128 * HDIM * 2;
    unsigned short* wtC1 = (unsigned short*)w;  w += 128 * HDIM * 2;
    unsigned short* wtC2 = (unsigned short*)w;  w += 128 * HDIM * 2;
    unsigned short* wtC3 = (unsigned short*)w;  w += 128 * HDIM * 2;
    unsigned short* wtT  = (unsigned short*)w;  w += 128 * HDIM * 2;
    unsigned short* wtB  = (unsigned short*)w;  w += 128 * HDIM * 2;

    int eg = (E + 255) / 256;
    int nb1 = (N + 255) / 256;
    int gemm_grid = (N + 63) / 64;
    int ag = (N + 3) / 4;
    long long eth = (long long)E * 16;
    int sg = (int)((eth + 255) / 256);

    // ---- weight prep (one pass, 7 matrices) ----
    WAll wa;
    wa.w[0] = { ew1,               wtE1, 256 };
    wa.w[1] = { ew2,               wtE2, 128 };
    wa.w[2] = { cw1,               wtC1, 128 };
    wa.w[3] = { cw2,               wtC2, 128 };
    wa.w[4] = { cw3,               wtC3, 128 };
    wa.w[5] = { clw1,              wtT,  128 };   // top half rows 0..127
    wa.w[6] = { clw1 + 128 * HDIM, wtB,  128 };   // bottom half rows 128..255
    k_prep_w<<<dim3(128, 7), 256, 0, stream>>>(wa);

    // ---- CSR build ----
    hipMemsetAsync(cnt, 0, Np * sizeof(int), stream);
    k_count<<<eg, 256, 0, stream>>>(ei + E, cnt, E);
    k_scan1<<<nb1, 256, 0, stream>>>(cnt, row_ptr, partial, N);
    k_scan2<<<1, 256, 0, stream>>>(partial, nb1);
    k_scan3<<<nb1, 256, 0, stream>>>(cnt, row_ptr, partial, cursor, dis, N, E);
    k_fill<<<eg, 256, 0, stream>>>(ei, ei + E, cursor, col, E);

    // ---- encoder ----
    k_gemm_nf<<<gemm_grid, 256, 0, stream>>>(nf, wtE1, eb1, bufA, N, 1);      // relu
    k_gemm_b<<<gemm_grid, 256, 0, stream>>>(bufA, wtE2, eb2, bufB, N, 0);     // x0

    // ---- conv1 ----
    k_gemm_b<<<gemm_grid, 256, 0, stream>>>(bufB, wtC1, nullptr, bufA, N, 0);
    k_aggregate<<<ag, 256, 0, stream>>>(row_ptr, col, dis, (const unsigned int*)bufA, cb1,
                                        (unsigned int*)bufC, N, 1);
    // ---- conv2 ----
    k_gemm_b<<<gemm_grid, 256, 0, stream>>>(bufC, wtC2, nullptr, bufB, N, 0);
    k_aggregate<<<ag, 256, 0, stream>>>(row_ptr, col, dis, (const unsigned int*)bufB, cb2,
                                        (unsigned int*)bufA, N, 1);
    // ---- conv3 (no relu) ----
    k_gemm_b<<<gemm_grid, 256, 0, stream>>>(bufA, wtC3, nullptr, bufC, N, 0);
    k_aggregate<<<ag, 256, 0, stream>>>(row_ptr, col, dis, (const unsigned int*)bufC, cb3,
                                        (unsigned int*)bufB, N, 0);          // x3

    // ---- edge classifier: P = x3@W1_top + b1, Q = x3@W1_bot ----
    k_gemm_b<<<gemm_grid, 256, 0, stream>>>(bufB, wtT, clb1, bufA, N, 0);
    k_gemm_b<<<gemm_grid, 256, 0, stream>>>(bufB, wtB, nullptr, bufC, N, 0);

    k_edge_score<<<sg, 256, 0, stream>>>(ei, bufA, bufC, clw2, clb2, out, E);
}

// Round 4
// 740.188 us; speedup vs baseline: 11.7344x; 1.0599x over previous
//
#include <hip/hip_runtime.h>
#include <math.h>

#define HDIM 128
#define BSH 7                 // bucket = dst >> 7 (128 nodes per bucket)
#define MAXBUCK 512

typedef __attribute__((ext_vector_type(8))) short    bf16x8;
typedef __attribute__((ext_vector_type(4))) float    f32x4;
typedef __attribute__((ext_vector_type(8))) unsigned short u16x8;
typedef __attribute__((ext_vector_type(4))) unsigned short u16x4;

__device__ __forceinline__ float bf2f(unsigned short u) {
    union { unsigned int i; float f; } c; c.i = ((unsigned int)u) << 16; return c.f;
}
__device__ __forceinline__ unsigned short f2bf(float f) {
    union { float f; unsigned int i; } c; c.f = f;
    unsigned int r = (c.i + 0x7fffu + ((c.i >> 16) & 1u)) >> 16;
    return (unsigned short)r;
}

// ---------------- CSR stage 1: per-node counts + per-block bucket histograms ----------------
__global__ __launch_bounds__(256) void k_count_hist(
    const int* __restrict__ dst, int* __restrict__ cnt, int* __restrict__ tot,
    int* __restrict__ hist, int E, int chunk, int nbuck)
{
    __shared__ int h[MAXBUCK];
    for (int i = threadIdx.x; i < MAXBUCK; i += 256) h[i] = 0;
    __syncthreads();
    int beg = blockIdx.x * chunk;
    int fin = min(beg + chunk, E);
    for (int e = beg + threadIdx.x; e < fin; e += 256) {
        int d = dst[e];
        atomicAdd(&cnt[d], 1);
        atomicAdd(&h[d >> BSH], 1);
    }
    __syncthreads();
    for (int k = threadIdx.x; k < nbuck; k += 256) {
        int v = h[k];
        hist[(size_t)blockIdx.x * nbuck + k] = v;
        if (v) atomicAdd(&tot[k], v);
    }
}

// ---------------- CSR stage 2: exclusive scan of bucket totals (1 block) ----------------
__global__ __launch_bounds__(256) void k_scan_buckets(
    const int* __restrict__ tot, int* __restrict__ gcur, int* __restrict__ base, int nbuck)
{
    __shared__ int a[MAXBUCK], b[MAXBUCK];
    int t = threadIdx.x;
    for (int i = t; i < MAXBUCK; i += 256) a[i] = (i < nbuck) ? tot[i] : 0;
    __syncthreads();
    int* s1 = a; int* s2 = b;
    for (int off = 1; off < MAXBUCK; off <<= 1) {
        for (int i = t; i < MAXBUCK; i += 256)
            s2[i] = s1[i] + ((i >= off) ? s1[i - off] : 0);
        __syncthreads();
        int* tmp = s1; s1 = s2; s2 = tmp;
    }
    // s1 = inclusive scan
    for (int i = t; i < nbuck; i += 256) {
        int e = (i == 0) ? 0 : s1[i - 1];
        gcur[i] = e;
        base[i] = e;
    }
    if (t == 0) base[nbuck] = s1[nbuck - 1];   // = E
}

// ---------------- CSR stage 3: partition edges into bucket segments (coalesced runs) ----------------
__global__ __launch_bounds__(256) void k_partition(
    const int* __restrict__ src, const int* __restrict__ dst,
    const int* __restrict__ hist, int* __restrict__ gcur,
    int2* __restrict__ stag, int E, int chunk, int nbuck)
{
    __shared__ int h[MAXBUCK];
    int t = threadIdx.x;
    // reserve contiguous run per (block,bucket)
    for (int k = t; k < nbuck; k += 256) {
        int v = hist[(size_t)blockIdx.x * nbuck + k];
        h[k] = v ? atomicAdd(&gcur[k], v) : 0;
    }
    __syncthreads();
    int beg = blockIdx.x * chunk;
    int fin = min(beg + chunk, E);
    for (int e = beg + t; e < fin; e += 256) {
        int d = dst[e];
        int s = src[e];
        int pos = atomicAdd(&h[d >> BSH], 1);
        stag[pos] = make_int2(s, d);
    }
}

// ---------------- CSR stage 4: per-bucket row_ptr + col scatter (L2-local) + dis ----------------
__global__ __launch_bounds__(256) void k_bucket_csr(
    const int* __restrict__ cnt, const int* __restrict__ base, const int2* __restrict__ stag,
    int* __restrict__ row_ptr, int* __restrict__ col, float* __restrict__ dis, int n, int nbuck)
{
    __shared__ int sa[128], sb[128], cur[128];
    int k = blockIdx.x;
    int n0 = k << BSH;
    int t = threadIdx.x;
    int cv = 0;
    if (t < 128) {
        int node = n0 + t;
        cv = (node < n) ? cnt[node] : 0;
        sa[t] = cv;
    }
    __syncthreads();
    int* s1 = sa; int* s2 = sb;
    for (int off = 1; off < 128; off <<= 1) {
        if (t < 128) s2[t] = s1[t] + ((t >= off) ? s1[t - off] : 0);
        __syncthreads();
        int* tmp = s1; s1 = s2; s2 = tmp;
    }
    int b0 = base[k];
    if (t < 128) {
        int node = n0 + t;
        if (node < n) {
            int rpv = b0 + s1[t] - cv;     // exclusive prefix
            row_ptr[node] = rpv;
            cur[t] = rpv;
            dis[node] = rsqrtf(1.0f + (float)cv);
        }
    }
    if (k == 0 && t == 0) row_ptr[n] = base[nbuck];
    __syncthreads();
    int m = base[k + 1] - b0;
    const int2* seg = stag + b0;
    for (int i = t; i < m; i += 256) {
        int2 e = seg[i];
        int pos = atomicAdd(&cur[e.y - n0], 1);
        col[pos] = e.x;
    }
}

// ---------------- weight prep: fp32 W[KxH] -> bf16 W^T[HxK] ----------------
struct WEnt { const float* src; unsigned short* dst; int K; };
struct WAll { WEnt w[7]; };

__global__ __launch_bounds__(256) void k_prep_w(WAll all) {
    WEnt e = all.w[blockIdx.y];
    int i = blockIdx.x * 256 + threadIdx.x;
    if (i >= e.K * HDIM) return;
    int k = i >> 7, c = i & 127;
    e.dst[(size_t)c * e.K + k] = f2bf(e.src[i]);
}

// ---------------- MFMA GEMM (bf16 A), K=128 ----------------
__global__ __launch_bounds__(256) void k_gemm_b(
    const unsigned short* __restrict__ X, const unsigned short* __restrict__ Wt,
    const float* __restrict__ bias, unsigned short* __restrict__ C,
    int M, int relu_out)
{
    const int K = 128;
    int wave = threadIdx.x >> 6, lane = threadIdx.x & 63;
    int quad = lane >> 4, r = lane & 15;
    int row0 = blockIdx.x * 64 + wave * 16;
    if (row0 >= M) return;
    const unsigned short* xp = X + (size_t)(row0 + r) * K + quad * 8;
    const unsigned short* wp = Wt + (size_t)r * K + quad * 8;
    f32x4 acc[8];
#pragma unroll
    for (int mt = 0; mt < 8; mt++) acc[mt] = (f32x4){0.f, 0.f, 0.f, 0.f};
#pragma unroll 2
    for (int k0 = 0; k0 < K; k0 += 32) {
        bf16x8 xf = *(const bf16x8*)(xp + k0);
#pragma unroll
        for (int mt = 0; mt < 8; mt++) {
            bf16x8 wf = *(const bf16x8*)(wp + (size_t)mt * 16 * K + k0);
            acc[mt] = __builtin_amdgcn_mfma_f32_16x16x32_bf16(wf, xf, acc[mt], 0, 0, 0);
        }
    }
    unsigned short* cp = C + (size_t)(row0 + r) * HDIM + quad * 4;
#pragma unroll
    for (int mt = 0; mt < 8; mt++) {
        u16x4 o;
#pragma unroll
        for (int j = 0; j < 4; j++) {
            float v = acc[mt][j];
            if (bias) v += bias[mt * 16 + quad * 4 + j];
            if (relu_out) v = fmaxf(v, 0.f);
            o[j] = f2bf(v);
        }
        *(u16x4*)(cp + mt * 16) = o;
    }
}

// ---------------- MFMA GEMM (fp32 A = node_features), K=256 ----------------
__global__ __launch_bounds__(256) void k_gemm_nf(
    const float* __restrict__ X, const unsigned short* __restrict__ Wt,
    const float* __restrict__ bias, unsigned short* __restrict__ C,
    int M, int relu_out)
{
    const int K = 256;
    int wave = threadIdx.x >> 6, lane = threadIdx.x & 63;
    int quad = lane >> 4, r = lane & 15;
    int row0 = blockIdx.x * 64 + wave * 16;
    if (row0 >= M) return;
    const float* xp = X + (size_t)(row0 + r) * K + quad * 8;
    const unsigned short* wp = Wt + (size_t)r * K + quad * 8;
    f32x4 acc[8];
#pragma unroll
    for (int mt = 0; mt < 8; mt++) acc[mt] = (f32x4){0.f, 0.f, 0.f, 0.f};
#pragma unroll 2
    for (int k0 = 0; k0 < K; k0 += 32) {
        float4 xa = *(const float4*)(xp + k0);
        float4 xb = *(const float4*)(xp + k0 + 4);
        bf16x8 xf;
        xf[0] = (short)f2bf(xa.x); xf[1] = (short)f2bf(xa.y);
        xf[2] = (short)f2bf(xa.z); xf[3] = (short)f2bf(xa.w);
        xf[4] = (short)f2bf(xb.x); xf[5] = (short)f2bf(xb.y);
        xf[6] = (short)f2bf(xb.z); xf[7] = (short)f2bf(xb.w);
#pragma unroll
        for (int mt = 0; mt < 8; mt++) {
            bf16x8 wf = *(const bf16x8*)(wp + (size_t)mt * 16 * K + k0);
            acc[mt] = __builtin_amdgcn_mfma_f32_16x16x32_bf16(wf, xf, acc[mt], 0, 0, 0);
        }
    }
    unsigned short* cp = C + (size_t)(row0 + r) * HDIM + quad * 4;
#pragma unroll
    for (int mt = 0; mt < 8; mt++) {
        u16x4 o;
#pragma unroll
        for (int j = 0; j < 4; j++) {
            float v = acc[mt][j];
            if (bias) v += bias[mt * 16 + quad * 4 + j];
            if (relu_out) v = fmaxf(v, 0.f);
            o[j] = f2bf(v);
        }
        *(u16x4*)(cp + mt * 16) = o;
    }
}

// ---------------- aggregate (bf16, quad-vectorized) ----------------
// wave per node; quad q handles neighbor j=beg+q+4i; lane loads ushort8 (16B) of the row.
__global__ __launch_bounds__(256) void k_aggregate(
    const int* __restrict__ row_ptr, const int* __restrict__ col,
    const float* __restrict__ dis, const unsigned short* __restrict__ xw,
    const float* __restrict__ bias, unsigned short* __restrict__ out, int n, int relu_out)
{
    int wid = (blockIdx.x * 256 + threadIdx.x) >> 6;
    if (wid >= n) return;
    int lane = threadIdx.x & 63;
    int q = lane >> 4, t = lane & 15;
    float di = dis[wid];
    float acc[8];
    u16x8 sv = *(const u16x8*)(xw + (size_t)wid * HDIM + t * 8);
#pragma unroll
    for (int f = 0; f < 8; f++) acc[f] = (q == 0) ? di * bf2f(sv[f]) : 0.f;
    int beg = row_ptr[wid], end = row_ptr[wid + 1];
    int j = beg + q;
    for (; j + 4 < end; j += 8) {
        int s0 = col[j], s1 = col[j + 4];
        float d0 = dis[s0], d1 = dis[s1];
        u16x8 v0 = *(const u16x8*)(xw + (size_t)s0 * HDIM + t * 8);
        u16x8 v1 = *(const u16x8*)(xw + (size_t)s1 * HDIM + t * 8);
#pragma unroll
        for (int f = 0; f < 8; f++)
            acc[f] += d0 * bf2f(v0[f]) + d1 * bf2f(v1[f]);
    }
    if (j < end) {
        int s = col[j];
        float ds = dis[s];
        u16x8 v = *(const u16x8*)(xw + (size_t)s * HDIM + t * 8);
#pragma unroll
        for (int f = 0; f < 8; f++) acc[f] += ds * bf2f(v[f]);
    }
#pragma unroll
    for (int f = 0; f < 8; f++) {
        acc[f] += __shfl_xor(acc[f], 16, 64);
        acc[f] += __shfl_xor(acc[f], 32, 64);
    }
    if (q == 0) {
        u16x8 o;
#pragma unroll
        for (int f = 0; f < 8; f++) {
            float v = di * acc[f] + bias[t * 8 + f];
            if (relu_out) v = fmaxf(v, 0.f);
            o[f] = f2bf(v);
        }
        *(u16x8*)(out + (size_t)wid * HDIM + t * 8) = o;
    }
}

// ---------------- edge scorer (bf16 P/Q) ----------------
__global__ __launch_bounds__(256) void k_edge_score(
    const int* __restrict__ ei, const unsigned short* __restrict__ P,
    const unsigned short* __restrict__ Q,
    const float* __restrict__ w2, const float* __restrict__ b2,
    float* __restrict__ out, int E)
{
    int gid = blockIdx.x * 256 + threadIdx.x;
    int e = gid >> 4;
    if (e >= E) return;
    int sub = gid & 15;
    int s = ei[e], d = ei[E + e];
    u16x8 pv = *(const u16x8*)(P + (size_t)s * HDIM + sub * 8);
    u16x8 qv = *(const u16x8*)(Q + (size_t)d * HDIM + sub * 8);
    float part = 0.f;
#pragma unroll
    for (int j = 0; j < 8; j++) {
        float h = bf2f(pv[j]) + bf2f(qv[j]);
        h = fmaxf(h, 0.f);
        part += h * w2[sub * 8 + j];
    }
#pragma unroll
    for (int off = 8; off; off >>= 1) part += __shfl_xor(part, off, 16);
    if (sub == 0) out[e] = 1.f / (1.f + expf(-(part + b2[0])));
}

extern "C" void kernel_launch(void* const* d_in, const int* in_sizes, int n_in,
                              void* d_out, int out_size, void* d_ws, size_t ws_size,
                              hipStream_t stream) {
    const float* nf   = (const float*)d_in[0];
    const int*   ei   = (const int*)d_in[1];
    const float* ew1  = (const float*)d_in[2];
    const float* eb1  = (const float*)d_in[3];
    const float* ew2  = (const float*)d_in[4];
    const float* eb2  = (const float*)d_in[5];
    const float* cw1  = (const float*)d_in[6];
    const float* cb1  = (const float*)d_in[7];
    const float* cw2  = (const float*)d_in[8];
    const float* cb2  = (const float*)d_in[9];
    const float* cw3  = (const float*)d_in[10];
    const float* cb3  = (const float*)d_in[11];
    const float* clw1 = (const float*)d_in[12];
    const float* clb1 = (const float*)d_in[13];
    const float* clw2 = (const float*)d_in[14];
    const float* clb2 = (const float*)d_in[15];
    float* out = (float*)d_out;

    const int FD = 256;
    const int N = in_sizes[0] / FD;
    const int E = in_sizes[1] / 2;
    const int NBUCK = (N + 127) >> BSH;          // <= MAXBUCK for N <= 65536
    const int PBLK = 256;                        // partition blocks
    const int chunk = (E + PBLK - 1) / PBLK;

    size_t Np = ((size_t)N + 256) & ~(size_t)255;
    char* w = (char*)d_ws;
    float* dis     = (float*)w;            w += Np * 4;
    int*   cnt     = (int*)w;              w += Np * 4;       // memset region start
    int*   tot     = (int*)w;              w += MAXBUCK * 4;  // memset region end
    int*   gcur    = (int*)w;              w += MAXBUCK * 4;
    int*   base    = (int*)w;              w += (MAXBUCK + 4) * 4;
    int*   hist    = (int*)w;              w += (size_t)PBLK * MAXBUCK * 4;
    int*   row_ptr = (int*)w;              w += Np * 4;
    int2*  stag    = (int2*)w;             w += (size_t)E * 8;
    int*   col     = (int*)w;              w += (((size_t)E * 4) + 255) & ~(size_t)255;
    unsigned short* bufA = (unsigned short*)w;  w += (size_t)N * HDIM * 2;
    unsigned short* bufB = (unsigned short*)w;  w += (size_t)N * HDIM * 2;
    unsigned short* bufC = (unsigned short*)w;  w += (size_t)N * HDIM * 2;
    unsigned short* wtE1 = (unsigned short*)w;  w += 256 * HDIM * 2;
    unsigned short* wtE2 = (unsigned short*)w;  w += 128 * HDIM * 2;
    unsigned short* wtC1 = (unsigned short*)w;  w += 128 * HDIM * 2;
    unsigned short* wtC2 = (unsigned short*)w;  w += 128 * HDIM * 2;
    unsigned short* wtC3 = (unsigned short*)w;  w += 128 * HDIM * 2;
    unsigned short* wtT  = (unsigned short*)w;  w += 128 * HDIM * 2;
    unsigned short* wtB  = (unsigned short*)w;  w += 128 * HDIM * 2;

    int gemm_grid = (N + 63) / 64;
    int ag = (N + 3) / 4;
    long long eth = (long long)E * 16;
    int sg = (int)((eth + 255) / 256);

    // ---- weight prep ----
    WAll wa;
    wa.w[0] = { ew1,               wtE1, 256 };
    wa.w[1] = { ew2,               wtE2, 128 };
    wa.w[2] = { cw1,               wtC1, 128 };
    wa.w[3] = { cw2,               wtC2, 128 };
    wa.w[4] = { cw3,               wtC3, 128 };
    wa.w[5] = { clw1,              wtT,  128 };
    wa.w[6] = { clw1 + 128 * HDIM, wtB,  128 };
    k_prep_w<<<dim3(128, 7), 256, 0, stream>>>(wa);

    // ---- CSR build (bucketed, write-coalesced) ----
    hipMemsetAsync(cnt, 0, (Np + MAXBUCK) * sizeof(int), stream);
    k_count_hist<<<PBLK, 256, 0, stream>>>(ei + E, cnt, tot, hist, E, chunk, NBUCK);
    k_scan_buckets<<<1, 256, 0, stream>>>(tot, gcur, base, NBUCK);
    k_partition<<<PBLK, 256, 0, stream>>>(ei, ei + E, hist, gcur, stag, E, chunk, NBUCK);
    k_bucket_csr<<<NBUCK, 256, 0, stream>>>(cnt, base, stag, row_ptr, col, dis, N, NBUCK);

    // ---- encoder ----
    k_gemm_nf<<<gemm_grid, 256, 0, stream>>>(nf, wtE1, eb1, bufA, N, 1);
    k_gemm_b<<<gemm_grid, 256, 0, stream>>>(bufA, wtE2, eb2, bufB, N, 0);

    // ---- conv1 ----
    k_gemm_b<<<gemm_grid, 256, 0, stream>>>(bufB, wtC1, nullptr, bufA, N, 0);
    k_aggregate<<<ag, 256, 0, stream>>>(row_ptr, col, dis, bufA, cb1, bufC, N, 1);
    // ---- conv2 ----
    k_gemm_b<<<gemm_grid, 256, 0, stream>>>(bufC, wtC2, nullptr, bufB, N, 0);
    k_aggregate<<<ag, 256, 0, stream>>>(row_ptr, col, dis, bufB, cb2, bufA, N, 1);
    // ---- conv3 (no relu) ----
    k_gemm_b<<<gemm_grid, 256, 0, stream>>>(bufA, wtC3, nullptr, bufC, N, 0);
    k_aggregate<<<ag, 256, 0, stream>>>(row_ptr, col, dis, bufC, cb3, bufB, N, 0);

    // ---- edge classifier: P = x3@W1_top + b1, Q = x3@W1_bot ----
    k_gemm_b<<<gemm_grid, 256, 0, stream>>>(bufB, wtT, clb1, bufA, N, 0);
    k_gemm_b<<<gemm_grid, 256, 0, stream>>>(bufB, wtB, nullptr, bufC, N, 0);

    k_edge_score<<<sg, 256, 0, stream>>>(ei, bufA, bufC, clw2, clb2, out, E);
}

// Round 5
// 618.930 us; speedup vs baseline: 14.0334x; 1.1959x over previous
//
#include <hip/hip_runtime.h>
#include <math.h>

#define HDIM 128
#define BSH 7                 // bucket = dst >> 7 (128 nodes per bucket)
#define MAXBUCK 512

typedef __attribute__((ext_vector_type(8))) short    bf16x8;
typedef __attribute__((ext_vector_type(4))) float    f32x4;
typedef __attribute__((ext_vector_type(2))) float    f32x2;
typedef __attribute__((ext_vector_type(8))) unsigned short u16x8;
typedef __attribute__((ext_vector_type(4))) unsigned short u16x4;

__device__ __forceinline__ float bf2f(unsigned short u) {
    union { unsigned int i; float f; } c; c.i = ((unsigned int)u) << 16; return c.f;
}
__device__ __forceinline__ unsigned short f2bf(float f) {
    union { float f; unsigned int i; } c; c.f = f;
    unsigned int r = (c.i + 0x7fffu + ((c.i >> 16) & 1u)) >> 16;
    return (unsigned short)r;
}
// decode 8 fp8 (e4m3) packed in uint2 -> 8 floats
__device__ __forceinline__ void f8x8_dec(uint2 v, float* f) {
    f32x2 a = __builtin_amdgcn_cvt_pk_f32_fp8((int)v.x, false);
    f32x2 b = __builtin_amdgcn_cvt_pk_f32_fp8((int)v.x, true);
    f32x2 c = __builtin_amdgcn_cvt_pk_f32_fp8((int)v.y, false);
    f32x2 d = __builtin_amdgcn_cvt_pk_f32_fp8((int)v.y, true);
    f[0] = a.x; f[1] = a.y; f[2] = b.x; f[3] = b.y;
    f[4] = c.x; f[5] = c.y; f[6] = d.x; f[7] = d.y;
}

// ---------------- CSR stage 1: per-node counts + per-block bucket histograms ----------------
__global__ __launch_bounds__(256) void k_count_hist(
    const int* __restrict__ dst, int* __restrict__ cnt, int* __restrict__ tot,
    int* __restrict__ hist, int E, int chunk, int nbuck)
{
    __shared__ int h[MAXBUCK];
    for (int i = threadIdx.x; i < MAXBUCK; i += 256) h[i] = 0;
    __syncthreads();
    int beg = blockIdx.x * chunk;
    int fin = min(beg + chunk, E);
    for (int e = beg + threadIdx.x; e < fin; e += 256) {
        int d = dst[e];
        atomicAdd(&cnt[d], 1);
        atomicAdd(&h[d >> BSH], 1);
    }
    __syncthreads();
    for (int k = threadIdx.x; k < nbuck; k += 256) {
        int v = h[k];
        hist[(size_t)blockIdx.x * nbuck + k] = v;
        if (v) atomicAdd(&tot[k], v);
    }
}

// ---------------- CSR stage 2: exclusive scan of bucket totals (1 block) ----------------
__global__ __launch_bounds__(256) void k_scan_buckets(
    const int* __restrict__ tot, int* __restrict__ gcur, int* __restrict__ base, int nbuck)
{
    __shared__ int a[MAXBUCK], b[MAXBUCK];
    int t = threadIdx.x;
    for (int i = t; i < MAXBUCK; i += 256) a[i] = (i < nbuck) ? tot[i] : 0;
    __syncthreads();
    int* s1 = a; int* s2 = b;
    for (int off = 1; off < MAXBUCK; off <<= 1) {
        for (int i = t; i < MAXBUCK; i += 256)
            s2[i] = s1[i] + ((i >= off) ? s1[i - off] : 0);
        __syncthreads();
        int* tmp = s1; s1 = s2; s2 = tmp;
    }
    for (int i = t; i < nbuck; i += 256) {
        int e = (i == 0) ? 0 : s1[i - 1];
        gcur[i] = e;
        base[i] = e;
    }
    if (t == 0) base[nbuck] = s1[nbuck - 1];
}

// ---------------- CSR stage 3: partition edges into bucket segments ----------------
__global__ __launch_bounds__(256) void k_partition(
    const int* __restrict__ src, const int* __restrict__ dst,
    const int* __restrict__ hist, int* __restrict__ gcur,
    int2* __restrict__ stag, int E, int chunk, int nbuck)
{
    __shared__ int h[MAXBUCK];
    int t = threadIdx.x;
    for (int k = t; k < nbuck; k += 256) {
        int v = hist[(size_t)blockIdx.x * nbuck + k];
        h[k] = v ? atomicAdd(&gcur[k], v) : 0;
    }
    __syncthreads();
    int beg = blockIdx.x * chunk;
    int fin = min(beg + chunk, E);
    for (int e = beg + t; e < fin; e += 256) {
        int d = dst[e];
        int s = src[e];
        int pos = atomicAdd(&h[d >> BSH], 1);
        stag[pos] = make_int2(s, d);
    }
}

// ---------------- CSR stage 4: per-bucket row_ptr + col scatter + dis ----------------
__global__ __launch_bounds__(256) void k_bucket_csr(
    const int* __restrict__ cnt, const int* __restrict__ base, const int2* __restrict__ stag,
    int* __restrict__ row_ptr, int* __restrict__ col, float* __restrict__ dis, int n, int nbuck)
{
    __shared__ int sa[128], sb[128], cur[128];
    int k = blockIdx.x;
    int n0 = k << BSH;
    int t = threadIdx.x;
    int cv = 0;
    if (t < 128) {
        int node = n0 + t;
        cv = (node < n) ? cnt[node] : 0;
        sa[t] = cv;
    }
    __syncthreads();
    int* s1 = sa; int* s2 = sb;
    for (int off = 1; off < 128; off <<= 1) {
        if (t < 128) s2[t] = s1[t] + ((t >= off) ? s1[t - off] : 0);
        __syncthreads();
        int* tmp = s1; s1 = s2; s2 = tmp;
    }
    int b0 = base[k];
    if (t < 128) {
        int node = n0 + t;
        if (node < n) {
            int rpv = b0 + s1[t] - cv;
            row_ptr[node] = rpv;
            cur[t] = rpv;
            dis[node] = rsqrtf(1.0f + (float)cv);
        }
    }
    if (k == 0 && t == 0) row_ptr[n] = base[nbuck];
    __syncthreads();
    int m = base[k + 1] - b0;
    const int2* seg = stag + b0;
    for (int i = t; i < m; i += 256) {
        int2 e = seg[i];
        int pos = atomicAdd(&cur[e.y - n0], 1);
        col[pos] = e.x;
    }
}

// ---------------- weight prep: fp32 W[KxH] -> bf16 W^T[HxK] ----------------
struct WEnt { const float* src; unsigned short* dst; int K; };
struct WAll { WEnt w[7]; };

__global__ __launch_bounds__(256) void k_prep_w(WAll all) {
    WEnt e = all.w[blockIdx.y];
    int i = blockIdx.x * 256 + threadIdx.x;
    if (i >= e.K * HDIM) return;
    int k = i >> 7, c = i & 127;
    e.dst[(size_t)c * e.K + k] = f2bf(e.src[i]);
}

// ---------------- MFMA GEMM (bf16 A), K=128; out bf16 or fp8 ----------------
__global__ __launch_bounds__(256) void k_gemm_b(
    const unsigned short* __restrict__ X, const unsigned short* __restrict__ Wt,
    const float* __restrict__ bias, void* __restrict__ C,
    int M, int relu_out, int out_fp8)
{
    const int K = 128;
    int wave = threadIdx.x >> 6, lane = threadIdx.x & 63;
    int quad = lane >> 4, r = lane & 15;
    int row0 = blockIdx.x * 64 + wave * 16;
    if (row0 >= M) return;
    const unsigned short* xp = X + (size_t)(row0 + r) * K + quad * 8;
    const unsigned short* wp = Wt + (size_t)r * K + quad * 8;
    f32x4 acc[8];
#pragma unroll
    for (int mt = 0; mt < 8; mt++) acc[mt] = (f32x4){0.f, 0.f, 0.f, 0.f};
#pragma unroll 2
    for (int k0 = 0; k0 < K; k0 += 32) {
        bf16x8 xf = *(const bf16x8*)(xp + k0);
#pragma unroll
        for (int mt = 0; mt < 8; mt++) {
            bf16x8 wf = *(const bf16x8*)(wp + (size_t)mt * 16 * K + k0);
            acc[mt] = __builtin_amdgcn_mfma_f32_16x16x32_bf16(wf, xf, acc[mt], 0, 0, 0);
        }
    }
    if (out_fp8) {
        unsigned char* cp = (unsigned char*)C + (size_t)(row0 + r) * HDIM + quad * 4;
#pragma unroll
        for (int mt = 0; mt < 8; mt++) {
            float v[4];
#pragma unroll
            for (int j = 0; j < 4; j++) {
                float x = acc[mt][j];
                if (bias) x += bias[mt * 16 + quad * 4 + j];
                if (relu_out) x = fmaxf(x, 0.f);
                v[j] = x;
            }
            int wd = 0;
            wd = __builtin_amdgcn_cvt_pk_fp8_f32(v[0], v[1], wd, false);
            wd = __builtin_amdgcn_cvt_pk_fp8_f32(v[2], v[3], wd, true);
            *(unsigned int*)(cp + mt * 16) = (unsigned int)wd;
        }
    } else {
        unsigned short* cp = (unsigned short*)C + (size_t)(row0 + r) * HDIM + quad * 4;
#pragma unroll
        for (int mt = 0; mt < 8; mt++) {
            u16x4 o;
#pragma unroll
            for (int j = 0; j < 4; j++) {
                float v = acc[mt][j];
                if (bias) v += bias[mt * 16 + quad * 4 + j];
                if (relu_out) v = fmaxf(v, 0.f);
                o[j] = f2bf(v);
            }
            *(u16x4*)(cp + mt * 16) = o;
        }
    }
}

// ---------------- MFMA GEMM (fp32 A = node_features), K=256, out bf16 ----------------
__global__ __launch_bounds__(256) void k_gemm_nf(
    const float* __restrict__ X, const unsigned short* __restrict__ Wt,
    const float* __restrict__ bias, unsigned short* __restrict__ C,
    int M, int relu_out)
{
    const int K = 256;
    int wave = threadIdx.x >> 6, lane = threadIdx.x & 63;
    int quad = lane >> 4, r = lane & 15;
    int row0 = blockIdx.x * 64 + wave * 16;
    if (row0 >= M) return;
    const float* xp = X + (size_t)(row0 + r) * K + quad * 8;
    const unsigned short* wp = Wt + (size_t)r * K + quad * 8;
    f32x4 acc[8];
#pragma unroll
    for (int mt = 0; mt < 8; mt++) acc[mt] = (f32x4){0.f, 0.f, 0.f, 0.f};
#pragma unroll 2
    for (int k0 = 0; k0 < K; k0 += 32) {
        float4 xa = *(const float4*)(xp + k0);
        float4 xb = *(const float4*)(xp + k0 + 4);
        bf16x8 xf;
        xf[0] = (short)f2bf(xa.x); xf[1] = (short)f2bf(xa.y);
        xf[2] = (short)f2bf(xa.z); xf[3] = (short)f2bf(xa.w);
        xf[4] = (short)f2bf(xb.x); xf[5] = (short)f2bf(xb.y);
        xf[6] = (short)f2bf(xb.z); xf[7] = (short)f2bf(xb.w);
#pragma unroll
        for (int mt = 0; mt < 8; mt++) {
            bf16x8 wf = *(const bf16x8*)(wp + (size_t)mt * 16 * K + k0);
            acc[mt] = __builtin_amdgcn_mfma_f32_16x16x32_bf16(wf, xf, acc[mt], 0, 0, 0);
        }
    }
    unsigned short* cp = C + (size_t)(row0 + r) * HDIM + quad * 4;
#pragma unroll
    for (int mt = 0; mt < 8; mt++) {
        u16x4 o;
#pragma unroll
        for (int j = 0; j < 4; j++) {
            float v = acc[mt][j];
            if (bias) v += bias[mt * 16 + quad * 4 + j];
            if (relu_out) v = fmaxf(v, 0.f);
            o[j] = f2bf(v);
        }
        *(u16x4*)(cp + mt * 16) = o;
    }
}

// ---------------- aggregate (fp8 gather -> bf16 out) ----------------
// wave per node; quad q handles neighbor j=beg+q+4i; lane loads uint2 (8 fp8) of the row.
__global__ __launch_bounds__(256) void k_aggregate_f8(
    const int* __restrict__ row_ptr, const int* __restrict__ col,
    const float* __restrict__ dis, const uint2* __restrict__ xw8,
    const float* __restrict__ bias, unsigned short* __restrict__ out, int n, int relu_out)
{
    int wid = (blockIdx.x * 256 + threadIdx.x) >> 6;
    if (wid >= n) return;
    int lane = threadIdx.x & 63;
    int q = lane >> 4, t = lane & 15;
    float di = dis[wid];
    float acc[8];
    {
        uint2 sv = xw8[(size_t)wid * 16 + t];
        float f[8]; f8x8_dec(sv, f);
#pragma unroll
        for (int i = 0; i < 8; i++) acc[i] = (q == 0) ? di * f[i] : 0.f;
    }
    int beg = row_ptr[wid], end = row_ptr[wid + 1];
    int j = beg + q;
    for (; j + 4 < end; j += 8) {
        int s0 = col[j], s1 = col[j + 4];
        float d0 = dis[s0], d1 = dis[s1];
        uint2 v0 = xw8[(size_t)s0 * 16 + t];
        uint2 v1 = xw8[(size_t)s1 * 16 + t];
        float f0[8], f1[8];
        f8x8_dec(v0, f0); f8x8_dec(v1, f1);
#pragma unroll
        for (int i = 0; i < 8; i++) acc[i] += d0 * f0[i] + d1 * f1[i];
    }
    if (j < end) {
        int s = col[j];
        float ds = dis[s];
        uint2 v = xw8[(size_t)s * 16 + t];
        float f[8]; f8x8_dec(v, f);
#pragma unroll
        for (int i = 0; i < 8; i++) acc[i] += ds * f[i];
    }
#pragma unroll
    for (int i = 0; i < 8; i++) {
        acc[i] += __shfl_xor(acc[i], 16, 64);
        acc[i] += __shfl_xor(acc[i], 32, 64);
    }
    if (q == 0) {
        u16x8 o;
#pragma unroll
        for (int i = 0; i < 8; i++) {
            float v = di * acc[i] + bias[t * 8 + i];
            if (relu_out) v = fmaxf(v, 0.f);
            o[i] = f2bf(v);
        }
        *(u16x8*)(out + (size_t)wid * HDIM + t * 8) = o;
    }
}

// ---------------- edge scorer (fp8 P/Q) ----------------
__global__ __launch_bounds__(256) void k_edge_score(
    const int* __restrict__ ei, const uint2* __restrict__ P8,
    const uint2* __restrict__ Q8,
    const float* __restrict__ w2, const float* __restrict__ b2,
    float* __restrict__ out, int E)
{
    int gid = blockIdx.x * 256 + threadIdx.x;
    int e = gid >> 4;
    if (e >= E) return;
    int sub = gid & 15;
    int s = ei[e], d = ei[E + e];
    uint2 pv = P8[(size_t)s * 16 + sub];
    uint2 qv = Q8[(size_t)d * 16 + sub];
    float pf[8], qf[8];
    f8x8_dec(pv, pf); f8x8_dec(qv, qf);
    float part = 0.f;
#pragma unroll
    for (int j = 0; j < 8; j++) {
        float h = fmaxf(pf[j] + qf[j], 0.f);
        part += h * w2[sub * 8 + j];
    }
#pragma unroll
    for (int off = 8; off; off >>= 1) part += __shfl_xor(part, off, 16);
    if (sub == 0) out[e] = 1.f / (1.f + expf(-(part + b2[0])));
}

extern "C" void kernel_launch(void* const* d_in, const int* in_sizes, int n_in,
                              void* d_out, int out_size, void* d_ws, size_t ws_size,
                              hipStream_t stream) {
    const float* nf   = (const float*)d_in[0];
    const int*   ei   = (const int*)d_in[1];
    const float* ew1  = (const float*)d_in[2];
    const float* eb1  = (const float*)d_in[3];
    const float* ew2  = (const float*)d_in[4];
    const float* eb2  = (const float*)d_in[5];
    const float* cw1  = (const float*)d_in[6];
    const float* cb1  = (const float*)d_in[7];
    const float* cw2  = (const float*)d_in[8];
    const float* cb2  = (const float*)d_in[9];
    const float* cw3  = (const float*)d_in[10];
    const float* cb3  = (const float*)d_in[11];
    const float* clw1 = (const float*)d_in[12];
    const float* clb1 = (const float*)d_in[13];
    const float* clw2 = (const float*)d_in[14];
    const float* clb2 = (const float*)d_in[15];
    float* out = (float*)d_out;

    const int FD = 256;
    const int N = in_sizes[0] / FD;
    const int E = in_sizes[1] / 2;
    const int NBUCK = (N + 127) >> BSH;
    const int PBLK = 256;
    const int chunk = (E + PBLK - 1) / PBLK;

    size_t Np = ((size_t)N + 256) & ~(size_t)255;
    char* w = (char*)d_ws;
    float* dis     = (float*)w;            w += Np * 4;
    int*   cnt     = (int*)w;              w += Np * 4;       // memset region start
    int*   tot     = (int*)w;              w += MAXBUCK * 4;  // memset region end
    int*   gcur    = (int*)w;              w += MAXBUCK * 4;
    int*   base    = (int*)w;              w += (MAXBUCK + 4) * 4;
    int*   hist    = (int*)w;              w += (size_t)PBLK * MAXBUCK * 4;
    int*   row_ptr = (int*)w;              w += Np * 4;
    int2*  stag    = (int2*)w;             w += (size_t)E * 8;   // reused later as P8/Q8
    int*   col     = (int*)w;              w += (((size_t)E * 4) + 255) & ~(size_t)255;
    unsigned short* bufA = (unsigned short*)w;  w += (size_t)N * HDIM * 2;
    unsigned short* bufB = (unsigned short*)w;  w += (size_t)N * HDIM * 2;
    unsigned short* bufC = (unsigned short*)w;  w += (size_t)N * HDIM * 2;
    unsigned char*  f8X  = (unsigned char*)w;   w += ((size_t)N * HDIM + 255) & ~(size_t)255;
    unsigned short* wtE1 = (unsigned short*)w;  w += 256 * HDIM * 2;
    unsigned short* wtE2 = (unsigned short*)w;  w += 128 * HDIM * 2;
    unsigned short* wtC1 = (unsigned short*)w;  w += 128 * HDIM * 2;
    unsigned short* wtC2 = (unsigned short*)w;  w += 128 * HDIM * 2;
    unsigned short* wtC3 = (unsigned short*)w;  w += 128 * HDIM * 2;
    unsigned short* wtT  = (unsigned short*)w;  w += 128 * HDIM * 2;
    unsigned short* wtB  = (unsigned short*)w;  w += 128 * HDIM * 2;

    // P8/Q8 alias the (dead-after-CSR) staging buffer: 2 * N*128 B <= E * 8 B
    unsigned char* f8P = (unsigned char*)stag;
    unsigned char* f8Q = f8P + (size_t)N * HDIM;

    int gemm_grid = (N + 63) / 64;
    int ag = (N + 3) / 4;
    long long eth = (long long)E * 16;
    int sg = (int)((eth + 255) / 256);

    // ---- weight prep ----
    WAll wa;
    wa.w[0] = { ew1,               wtE1, 256 };
    wa.w[1] = { ew2,               wtE2, 128 };
    wa.w[2] = { cw1,               wtC1, 128 };
    wa.w[3] = { cw2,               wtC2, 128 };
    wa.w[4] = { cw3,               wtC3, 128 };
    wa.w[5] = { clw1,              wtT,  128 };
    wa.w[6] = { clw1 + 128 * HDIM, wtB,  128 };
    k_prep_w<<<dim3(128, 7), 256, 0, stream>>>(wa);

    // ---- CSR build (bucketed, write-coalesced) ----
    hipMemsetAsync(cnt, 0, (Np + MAXBUCK) * sizeof(int), stream);
    k_count_hist<<<PBLK, 256, 0, stream>>>(ei + E, cnt, tot, hist, E, chunk, NBUCK);
    k_scan_buckets<<<1, 256, 0, stream>>>(tot, gcur, base, NBUCK);
    k_partition<<<PBLK, 256, 0, stream>>>(ei, ei + E, hist, gcur, stag, E, chunk, NBUCK);
    k_bucket_csr<<<NBUCK, 256, 0, stream>>>(cnt, base, stag, row_ptr, col, dis, N, NBUCK);

    // ---- encoder (bf16 throughout) ----
    k_gemm_nf<<<gemm_grid, 256, 0, stream>>>(nf, wtE1, eb1, bufA, N, 1);
    k_gemm_b<<<gemm_grid, 256, 0, stream>>>(bufA, wtE2, eb2, bufB, N, 0, 0);   // x0

    // ---- conv1: GEMM -> fp8 xw, aggregate -> bf16 ----
    k_gemm_b<<<gemm_grid, 256, 0, stream>>>(bufB, wtC1, nullptr, f8X, N, 0, 1);
    k_aggregate_f8<<<ag, 256, 0, stream>>>(row_ptr, col, dis, (const uint2*)f8X, cb1, bufC, N, 1);
    // ---- conv2 ----
    k_gemm_b<<<gemm_grid, 256, 0, stream>>>(bufC, wtC2, nullptr, f8X, N, 0, 1);
    k_aggregate_f8<<<ag, 256, 0, stream>>>(row_ptr, col, dis, (const uint2*)f8X, cb2, bufA, N, 1);
    // ---- conv3 (no relu) ----
    k_gemm_b<<<gemm_grid, 256, 0, stream>>>(bufA, wtC3, nullptr, f8X, N, 0, 1);
    k_aggregate_f8<<<ag, 256, 0, stream>>>(row_ptr, col, dis, (const uint2*)f8X, cb3, bufB, N, 0); // x3

    // ---- edge classifier: P = x3@W1_top + b1 (fp8), Q = x3@W1_bot (fp8) ----
    k_gemm_b<<<gemm_grid, 256, 0, stream>>>(bufB, wtT, clb1, f8P, N, 0, 1);
    k_gemm_b<<<gemm_grid, 256, 0, stream>>>(bufB, wtB, nullptr, f8Q, N, 0, 1);

    k_edge_score<<<sg, 256, 0, stream>>>(ei, (const uint2*)f8P, (const uint2*)f8Q, clw2, clb2, out, E);
}

// Round 6
// 553.182 us; speedup vs baseline: 15.7013x; 1.1189x over previous
//
#include <hip/hip_runtime.h>
#include <math.h>

#define HDIM 128
#define BSH 7                 // bucket = dst >> 7 (128 nodes per bucket)
#define MAXBUCK 512

typedef __attribute__((ext_vector_type(8))) short    bf16x8;
typedef __attribute__((ext_vector_type(4))) float    f32x4;
typedef __attribute__((ext_vector_type(2))) float    f32x2;
typedef __attribute__((ext_vector_type(8))) unsigned short u16x8;
typedef __attribute__((ext_vector_type(4))) unsigned short u16x4;

__device__ __forceinline__ float bf2f(unsigned short u) {
    union { unsigned int i; float f; } c; c.i = ((unsigned int)u) << 16; return c.f;
}
__device__ __forceinline__ unsigned short f2bf(float f) {
    union { float f; unsigned int i; } c; c.f = f;
    unsigned int r = (c.i + 0x7fffu + ((c.i >> 16) & 1u)) >> 16;
    return (unsigned short)r;
}
// decode 8 fp8 (e4m3) packed in uint2 -> 8 floats
__device__ __forceinline__ void f8x8_dec(uint2 v, float* f) {
    f32x2 a = __builtin_amdgcn_cvt_pk_f32_fp8((int)v.x, false);
    f32x2 b = __builtin_amdgcn_cvt_pk_f32_fp8((int)v.x, true);
    f32x2 c = __builtin_amdgcn_cvt_pk_f32_fp8((int)v.y, false);
    f32x2 d = __builtin_amdgcn_cvt_pk_f32_fp8((int)v.y, true);
    f[0] = a.x; f[1] = a.y; f[2] = b.x; f[3] = b.y;
    f[4] = c.x; f[5] = c.y; f[6] = d.x; f[7] = d.y;
}

// ---------------- CSR stage 1: per-block bucket histograms (LDS only) ----------------
__global__ __launch_bounds__(256) void k_hist(
    const int* __restrict__ dst, int* __restrict__ tot,
    int* __restrict__ hist, int E, int chunk, int nbuck)
{
    __shared__ int h[MAXBUCK];
    for (int i = threadIdx.x; i < MAXBUCK; i += 256) h[i] = 0;
    __syncthreads();
    int beg = blockIdx.x * chunk;
    int fin = min(beg + chunk, E);
    for (int e = beg + threadIdx.x; e < fin; e += 256)
        atomicAdd(&h[dst[e] >> BSH], 1);
    __syncthreads();
    for (int k = threadIdx.x; k < nbuck; k += 256) {
        int v = h[k];
        hist[(size_t)blockIdx.x * nbuck + k] = v;
        if (v) atomicAdd(&tot[k], v);
    }
}

// ---------------- CSR stage 2: exclusive scan of bucket totals (1 block) ----------------
__global__ __launch_bounds__(256) void k_scan_buckets(
    const int* __restrict__ tot, int* __restrict__ gcur, int* __restrict__ base, int nbuck)
{
    __shared__ int a[MAXBUCK], b[MAXBUCK];
    int t = threadIdx.x;
    for (int i = t; i < MAXBUCK; i += 256) a[i] = (i < nbuck) ? tot[i] : 0;
    __syncthreads();
    int* s1 = a; int* s2 = b;
    for (int off = 1; off < MAXBUCK; off <<= 1) {
        for (int i = t; i < MAXBUCK; i += 256)
            s2[i] = s1[i] + ((i >= off) ? s1[i - off] : 0);
        __syncthreads();
        int* tmp = s1; s1 = s2; s2 = tmp;
    }
    for (int i = t; i < nbuck; i += 256) {
        int e = (i == 0) ? 0 : s1[i - 1];
        gcur[i] = e;
        base[i] = e;
    }
    if (t == 0) base[nbuck] = s1[nbuck - 1];
}

// ---------------- CSR stage 3: partition edges into bucket segments (packed 4B) ----------------
__global__ __launch_bounds__(256) void k_partition(
    const int* __restrict__ src, const int* __restrict__ dst,
    const int* __restrict__ hist, int* __restrict__ gcur,
    unsigned int* __restrict__ stag, int E, int chunk, int nbuck)
{
    __shared__ int h[MAXBUCK];
    int t = threadIdx.x;
    for (int k = t; k < nbuck; k += 256) {
        int v = hist[(size_t)blockIdx.x * nbuck + k];
        h[k] = v ? atomicAdd(&gcur[k], v) : 0;
    }
    __syncthreads();
    int beg = blockIdx.x * chunk;
    int fin = min(beg + chunk, E);
    for (int e = beg + t; e < fin; e += 256) {
        int d = dst[e];
        unsigned int s = (unsigned int)src[e];
        int pos = atomicAdd(&h[d >> BSH], 1);
        stag[pos] = (s << BSH) | (unsigned int)(d & 127);
    }
}

// ---------------- CSR stage 4: per-bucket counts + row_ptr + col scatter + dis ----------------
__global__ __launch_bounds__(256) void k_bucket_csr(
    const int* __restrict__ base, const unsigned int* __restrict__ stag,
    int* __restrict__ row_ptr, int* __restrict__ col, float* __restrict__ dis, int n, int nbuck)
{
    __shared__ int cl[128], sa[128], sb[128], cur[128];
    int k = blockIdx.x;
    int n0 = k << BSH;
    int t = threadIdx.x;
    if (t < 128) cl[t] = 0;
    __syncthreads();
    int b0 = base[k];
    int m = base[k + 1] - b0;
    const unsigned int* seg = stag + b0;
    for (int i = t; i < m; i += 256) atomicAdd(&cl[seg[i] & 127], 1);
    __syncthreads();
    int cv = 0;
    if (t < 128) { cv = cl[t]; sa[t] = cv; }
    __syncthreads();
    int* s1 = sa; int* s2 = sb;
    for (int off = 1; off < 128; off <<= 1) {
        if (t < 128) s2[t] = s1[t] + ((t >= off) ? s1[t - off] : 0);
        __syncthreads();
        int* tmp = s1; s1 = s2; s2 = tmp;
    }
    if (t < 128) {
        int node = n0 + t;
        if (node < n) {
            int rpv = b0 + s1[t] - cv;
            row_ptr[node] = rpv;
            cur[t] = rpv;
            dis[node] = rsqrtf(1.0f + (float)cv);
        }
    }
    if (k == 0 && t == 0) row_ptr[n] = base[nbuck];
    __syncthreads();
    for (int i = t; i < m; i += 256) {
        unsigned int e = seg[i];
        int pos = atomicAdd(&cur[e & 127], 1);
        col[pos] = (int)(e >> BSH);
    }
}

// ---------------- weight prep: fp32 W[KxH] -> bf16 W^T[HxK] ----------------
struct WEnt { const float* src; unsigned short* dst; int K; };
struct WAll { WEnt w[7]; };

__global__ __launch_bounds__(256) void k_prep_w(WAll all) {
    WEnt e = all.w[blockIdx.y];
    int i = blockIdx.x * 256 + threadIdx.x;
    if (i >= e.K * HDIM) return;
    int k = i >> 7, c = i & 127;
    e.dst[(size_t)c * e.K + k] = f2bf(e.src[i]);
}

// ---------------- MFMA GEMM (bf16 A), K=128; out bf16 or fp8, optional row-scale ----------------
__global__ __launch_bounds__(256) void k_gemm_b(
    const unsigned short* __restrict__ X, const unsigned short* __restrict__ Wt,
    const float* __restrict__ bias, const float* __restrict__ scale,
    void* __restrict__ C, int M, int relu_out, int out_fp8)
{
    const int K = 128;
    int wave = threadIdx.x >> 6, lane = threadIdx.x & 63;
    int quad = lane >> 4, r = lane & 15;
    int row0 = blockIdx.x * 64 + wave * 16;
    if (row0 >= M) return;
    const unsigned short* xp = X + (size_t)(row0 + r) * K + quad * 8;
    const unsigned short* wp = Wt + (size_t)r * K + quad * 8;
    f32x4 acc[8];
#pragma unroll
    for (int mt = 0; mt < 8; mt++) acc[mt] = (f32x4){0.f, 0.f, 0.f, 0.f};
#pragma unroll 2
    for (int k0 = 0; k0 < K; k0 += 32) {
        bf16x8 xf = *(const bf16x8*)(xp + k0);
#pragma unroll
        for (int mt = 0; mt < 8; mt++) {
            bf16x8 wf = *(const bf16x8*)(wp + (size_t)mt * 16 * K + k0);
            acc[mt] = __builtin_amdgcn_mfma_f32_16x16x32_bf16(wf, xf, acc[mt], 0, 0, 0);
        }
    }
    float sc = scale ? scale[row0 + r] : 1.f;
    if (out_fp8) {
        unsigned char* cp = (unsigned char*)C + (size_t)(row0 + r) * HDIM + quad * 4;
#pragma unroll
        for (int mt = 0; mt < 8; mt++) {
            float v[4];
#pragma unroll
            for (int j = 0; j < 4; j++) {
                float x = acc[mt][j];
                if (bias) x += bias[mt * 16 + quad * 4 + j];
                if (relu_out) x = fmaxf(x, 0.f);
                v[j] = x * sc;
            }
            int wd = 0;
            wd = __builtin_amdgcn_cvt_pk_fp8_f32(v[0], v[1], wd, false);
            wd = __builtin_amdgcn_cvt_pk_fp8_f32(v[2], v[3], wd, true);
            *(unsigned int*)(cp + mt * 16) = (unsigned int)wd;
        }
    } else {
        unsigned short* cp = (unsigned short*)C + (size_t)(row0 + r) * HDIM + quad * 4;
#pragma unroll
        for (int mt = 0; mt < 8; mt++) {
            u16x4 o;
#pragma unroll
            for (int j = 0; j < 4; j++) {
                float v = acc[mt][j];
                if (bias) v += bias[mt * 16 + quad * 4 + j];
                if (relu_out) v = fmaxf(v, 0.f);
                o[j] = f2bf(v * sc);
            }
            *(u16x4*)(cp + mt * 16) = o;
        }
    }
}

// ---------------- MFMA GEMM (fp32 A = node_features), K=256, out bf16 ----------------
__global__ __launch_bounds__(256) void k_gemm_nf(
    const float* __restrict__ X, const unsigned short* __restrict__ Wt,
    const float* __restrict__ bias, unsigned short* __restrict__ C,
    int M, int relu_out)
{
    const int K = 256;
    int wave = threadIdx.x >> 6, lane = threadIdx.x & 63;
    int quad = lane >> 4, r = lane & 15;
    int row0 = blockIdx.x * 64 + wave * 16;
    if (row0 >= M) return;
    const float* xp = X + (size_t)(row0 + r) * K + quad * 8;
    const unsigned short* wp = Wt + (size_t)r * K + quad * 8;
    f32x4 acc[8];
#pragma unroll
    for (int mt = 0; mt < 8; mt++) acc[mt] = (f32x4){0.f, 0.f, 0.f, 0.f};
#pragma unroll 2
    for (int k0 = 0; k0 < K; k0 += 32) {
        float4 xa = *(const float4*)(xp + k0);
        float4 xb = *(const float4*)(xp + k0 + 4);
        bf16x8 xf;
        xf[0] = (short)f2bf(xa.x); xf[1] = (short)f2bf(xa.y);
        xf[2] = (short)f2bf(xa.z); xf[3] = (short)f2bf(xa.w);
        xf[4] = (short)f2bf(xb.x); xf[5] = (short)f2bf(xb.y);
        xf[6] = (short)f2bf(xb.z); xf[7] = (short)f2bf(xb.w);
#pragma unroll
        for (int mt = 0; mt < 8; mt++) {
            bf16x8 wf = *(const bf16x8*)(wp + (size_t)mt * 16 * K + k0);
            acc[mt] = __builtin_amdgcn_mfma_f32_16x16x32_bf16(wf, xf, acc[mt], 0, 0, 0);
        }
    }
    unsigned short* cp = C + (size_t)(row0 + r) * HDIM + quad * 4;
#pragma unroll
    for (int mt = 0; mt < 8; mt++) {
        u16x4 o;
#pragma unroll
        for (int j = 0; j < 4; j++) {
            float v = acc[mt][j];
            if (bias) v += bias[mt * 16 + quad * 4 + j];
            if (relu_out) v = fmaxf(v, 0.f);
            o[j] = f2bf(v);
        }
        *(u16x4*)(cp + mt * 16) = o;
    }
}

// ---------------- aggregate (pre-scaled fp8 y-table): out[i] = di*(y[i] + sum_nbr y[s]) + b ----------------
__global__ __launch_bounds__(256) void k_aggregate_f8(
    const int* __restrict__ row_ptr, const int* __restrict__ col,
    const float* __restrict__ dis, const uint2* __restrict__ y8,
    const float* __restrict__ bias, unsigned short* __restrict__ out, int n, int relu_out)
{
    int wid = (blockIdx.x * 256 + threadIdx.x) >> 6;
    if (wid >= n) return;
    int lane = threadIdx.x & 63;
    int q = lane >> 4, t = lane & 15;
    float acc[8];
    {
        uint2 sv = y8[(size_t)wid * 16 + t];        // self term y[i]
        float f[8]; f8x8_dec(sv, f);
#pragma unroll
        for (int i = 0; i < 8; i++) acc[i] = (q == 0) ? f[i] : 0.f;
    }
    int beg = row_ptr[wid], end = row_ptr[wid + 1];
    int j = beg + q;
    for (; j + 4 < end; j += 8) {
        int s0 = col[j], s1 = col[j + 4];
        uint2 v0 = y8[(size_t)s0 * 16 + t];
        uint2 v1 = y8[(size_t)s1 * 16 + t];
        float f0[8], f1[8];
        f8x8_dec(v0, f0); f8x8_dec(v1, f1);
#pragma unroll
        for (int i = 0; i < 8; i++) acc[i] += f0[i] + f1[i];
    }
    if (j < end) {
        int s = col[j];
        uint2 v = y8[(size_t)s * 16 + t];
        float f[8]; f8x8_dec(v, f);
#pragma unroll
        for (int i = 0; i < 8; i++) acc[i] += f[i];
    }
#pragma unroll
    for (int i = 0; i < 8; i++) {
        acc[i] += __shfl_xor(acc[i], 16, 64);
        acc[i] += __shfl_xor(acc[i], 32, 64);
    }
    if (q == 0) {
        float di = dis[wid];
        u16x8 o;
#pragma unroll
        for (int i = 0; i < 8; i++) {
            float v = di * acc[i] + bias[t * 8 + i];
            if (relu_out) v = fmaxf(v, 0.f);
            o[i] = f2bf(v);
        }
        *(u16x8*)(out + (size_t)wid * HDIM + t * 8) = o;
    }
}

// ---------------- edge scorer (fp8 P/Q, persistent grid-stride, w2 hoisted) ----------------
__global__ __launch_bounds__(256) void k_edge_score(
    const int* __restrict__ ei, const uint2* __restrict__ P8,
    const uint2* __restrict__ Q8,
    const float* __restrict__ w2, const float* __restrict__ b2,
    float* __restrict__ out, int E)
{
    int tid = blockIdx.x * 256 + threadIdx.x;
    int sub = tid & 15;
    float w[8];
#pragma unroll
    for (int j = 0; j < 8; j++) w[j] = w2[sub * 8 + j];
    float bb = b2[0];
    int e0 = tid >> 4;
    int stride = (gridDim.x * 256) >> 4;
    for (int e = e0; e < E; e += stride) {
        int s = ei[e], d = ei[E + e];
        uint2 pv = P8[(size_t)s * 16 + sub];
        uint2 qv = Q8[(size_t)d * 16 + sub];
        float pf[8], qf[8];
        f8x8_dec(pv, pf); f8x8_dec(qv, qf);
        float part = 0.f;
#pragma unroll
        for (int j = 0; j < 8; j++)
            part += fmaxf(pf[j] + qf[j], 0.f) * w[j];
        part += __shfl_xor(part, 8, 16);
        part += __shfl_xor(part, 4, 16);
        part += __shfl_xor(part, 2, 16);
        part += __shfl_xor(part, 1, 16);
        if (sub == 0) out[e] = 1.f / (1.f + expf(-(part + bb)));
    }
}

extern "C" void kernel_launch(void* const* d_in, const int* in_sizes, int n_in,
                              void* d_out, int out_size, void* d_ws, size_t ws_size,
                              hipStream_t stream) {
    const float* nf   = (const float*)d_in[0];
    const int*   ei   = (const int*)d_in[1];
    const float* ew1  = (const float*)d_in[2];
    const float* eb1  = (const float*)d_in[3];
    const float* ew2  = (const float*)d_in[4];
    const float* eb2  = (const float*)d_in[5];
    const float* cw1  = (const float*)d_in[6];
    const float* cb1  = (const float*)d_in[7];
    const float* cw2  = (const float*)d_in[8];
    const float* cb2  = (const float*)d_in[9];
    const float* cw3  = (const float*)d_in[10];
    const float* cb3  = (const float*)d_in[11];
    const float* clw1 = (const float*)d_in[12];
    const float* clb1 = (const float*)d_in[13];
    const float* clw2 = (const float*)d_in[14];
    const float* clb2 = (const float*)d_in[15];
    float* out = (float*)d_out;

    const int FD = 256;
    const int N = in_sizes[0] / FD;
    const int E = in_sizes[1] / 2;
    const int NBUCK = (N + 127) >> BSH;
    const int PBLK = 256;
    const int chunk = (E + PBLK - 1) / PBLK;

    size_t Np = ((size_t)N + 256) & ~(size_t)255;
    char* w = (char*)d_ws;
    float* dis     = (float*)w;            w += Np * 4;
    int*   tot     = (int*)w;              w += MAXBUCK * 4;   // memset region
    int*   gcur    = (int*)w;              w += MAXBUCK * 4;
    int*   base    = (int*)w;              w += (MAXBUCK + 4) * 4;
    int*   hist    = (int*)w;              w += (size_t)PBLK * MAXBUCK * 4;
    int*   row_ptr = (int*)w;              w += Np * 4;
    unsigned int* stag = (unsigned int*)w; w += (size_t)E * 4;
    int*   col     = (int*)w;              w += (((size_t)E * 4) + 255) & ~(size_t)255;
    unsigned short* bufA = (unsigned short*)w;  w += (size_t)N * HDIM * 2;
    unsigned short* bufB = (unsigned short*)w;  w += (size_t)N * HDIM * 2;
    unsigned short* bufC = (unsigned short*)w;  w += (size_t)N * HDIM * 2;
    unsigned char*  f8X  = (unsigned char*)w;   w += ((size_t)N * HDIM + 255) & ~(size_t)255;
    unsigned char*  f8P  = (unsigned char*)w;   w += ((size_t)N * HDIM + 255) & ~(size_t)255;
    unsigned char*  f8Q  = (unsigned char*)w;   w += ((size_t)N * HDIM + 255) & ~(size_t)255;
    unsigned short* wtE1 = (unsigned short*)w;  w += 256 * HDIM * 2;
    unsigned short* wtE2 = (unsigned short*)w;  w += 128 * HDIM * 2;
    unsigned short* wtC1 = (unsigned short*)w;  w += 128 * HDIM * 2;
    unsigned short* wtC2 = (unsigned short*)w;  w += 128 * HDIM * 2;
    unsigned short* wtC3 = (unsigned short*)w;  w += 128 * HDIM * 2;
    unsigned short* wtT  = (unsigned short*)w;  w += 128 * HDIM * 2;
    unsigned short* wtB  = (unsigned short*)w;  w += 128 * HDIM * 2;

    int gemm_grid = (N + 63) / 64;
    int ag = (N + 3) / 4;

    // ---- weight prep ----
    WAll wa;
    wa.w[0] = { ew1,               wtE1, 256 };
    wa.w[1] = { ew2,               wtE2, 128 };
    wa.w[2] = { cw1,               wtC1, 128 };
    wa.w[3] = { cw2,               wtC2, 128 };
    wa.w[4] = { cw3,               wtC3, 128 };
    wa.w[5] = { clw1,              wtT,  128 };
    wa.w[6] = { clw1 + 128 * HDIM, wtB,  128 };
    k_prep_w<<<dim3(128, 7), 256, 0, stream>>>(wa);

    // ---- CSR build (bucketed, packed staging, LDS counts) ----
    hipMemsetAsync(tot, 0, MAXBUCK * sizeof(int), stream);
    k_hist<<<PBLK, 256, 0, stream>>>(ei + E, tot, hist, E, chunk, NBUCK);
    k_scan_buckets<<<1, 256, 0, stream>>>(tot, gcur, base, NBUCK);
    k_partition<<<PBLK, 256, 0, stream>>>(ei, ei + E, hist, gcur, stag, E, chunk, NBUCK);
    k_bucket_csr<<<NBUCK, 256, 0, stream>>>(base, stag, row_ptr, col, dis, N, NBUCK);

    // ---- encoder (bf16) ----
    k_gemm_nf<<<gemm_grid, 256, 0, stream>>>(nf, wtE1, eb1, bufA, N, 1);
    k_gemm_b<<<gemm_grid, 256, 0, stream>>>(bufA, wtE2, eb2, nullptr, bufB, N, 0, 0);  // x0

    // ---- conv1: y = dis*(x0@W) as fp8; aggregate -> bf16 ----
    k_gemm_b<<<gemm_grid, 256, 0, stream>>>(bufB, wtC1, nullptr, dis, f8X, N, 0, 1);
    k_aggregate_f8<<<ag, 256, 0, stream>>>(row_ptr, col, dis, (const uint2*)f8X, cb1, bufC, N, 1);
    // ---- conv2 ----
    k_gemm_b<<<gemm_grid, 256, 0, stream>>>(bufC, wtC2, nullptr, dis, f8X, N, 0, 1);
    k_aggregate_f8<<<ag, 256, 0, stream>>>(row_ptr, col, dis, (const uint2*)f8X, cb2, bufA, N, 1);
    // ---- conv3 (no relu) ----
    k_gemm_b<<<gemm_grid, 256, 0, stream>>>(bufA, wtC3, nullptr, dis, f8X, N, 0, 1);
    k_aggregate_f8<<<ag, 256, 0, stream>>>(row_ptr, col, dis, (const uint2*)f8X, cb3, bufB, N, 0); // x3

    // ---- edge classifier: P = x3@W1_top + b1 (fp8), Q = x3@W1_bot (fp8) ----
    k_gemm_b<<<gemm_grid, 256, 0, stream>>>(bufB, wtT, clb1, nullptr, f8P, N, 0, 1);
    k_gemm_b<<<gemm_grid, 256, 0, stream>>>(bufB, wtB, nullptr, nullptr, f8Q, N, 0, 1);

    k_edge_score<<<2048, 256, 0, stream>>>(ei, (const uint2*)f8P, (const uint2*)f8Q, clw2, clb2, out, E);
}